// Round 9
// baseline (1030.063 us; speedup 1.0000x reference)
//
#include <hip/hip_runtime.h>
#include <hip/hip_bf16.h>

typedef unsigned short u16;
typedef unsigned int u32;
typedef float f32x4 __attribute__((ext_vector_type(4)));
typedef short bf16x8 __attribute__((ext_vector_type(8)));
typedef unsigned short u16x4 __attribute__((ext_vector_type(4)));
typedef unsigned int u32x2 __attribute__((ext_vector_type(2)));
typedef unsigned int u32x4 __attribute__((ext_vector_type(4)));

#define BT 2048            // B*T
#define DMODEL 2048
#define HV 32
#define DK 128
#define KEYDIM 2048
#define VALDIM 4096
#define QKVZ_N 12288
#define CONVC 8192         // q,k,v channels
#define INTER 8192

__device__ __forceinline__ float bf2f(u16 v) {
  u32 u = ((u32)v) << 16;
  return __builtin_bit_cast(float, u);
}
__device__ __forceinline__ u16 f2bf(float f) {
  u32 u = __builtin_bit_cast(u32, f);
  u32 r = (u + 0x7fffu + ((u >> 16) & 1u)) >> 16;
  return (u16)r;
}
__device__ __forceinline__ u32 pack2(float a, float b) {
  return (u32)f2bf(a) | ((u32)f2bf(b) << 16);
}
__device__ __forceinline__ float siluf(float x) {
  return x / (1.f + expf(-x));
}

// -------- weight convert+transpose: W[K,N] f32 (row stride ldw) -> Wt[N,K] bf16
__global__ __launch_bounds__(256) void convert_transpose(
    const float* __restrict__ W, int ldw, u16* __restrict__ Wt, int K, int N) {
  __shared__ float tile[32][33];
  int n0 = blockIdx.x * 32, k0 = blockIdx.y * 32;
  int tx = threadIdx.x & 31, ty = threadIdx.x >> 5;  // ty 0..7
#pragma unroll
  for (int i = 0; i < 4; ++i) {
    int kk = ty + i * 8;
    tile[kk][tx] = W[(size_t)(k0 + kk) * ldw + n0 + tx];
  }
  __syncthreads();
#pragma unroll
  for (int i = 0; i < 4; ++i) {
    int nn = ty + i * 8;
    Wt[(size_t)(n0 + nn) * K + k0 + tx] = f2bf(tile[tx][nn]);
  }
}

// -------- fused residual add + gemma RMSNorm (a+b -> resout f32, norm -> bf16)
__global__ __launch_bounds__(256) void resnorm_kernel(
    const float* __restrict__ a, const float* __restrict__ b,
    const float* __restrict__ w, float* __restrict__ resout,
    u16* __restrict__ hb) {
  int tok = blockIdx.x, t = threadIdx.x;
  const float* ap = a + (size_t)tok * DMODEL + t * 8;
  const float* bp = b + (size_t)tok * DMODEL + t * 8;
  f32x4 x0 = *(const f32x4*)ap + *(const f32x4*)bp;
  f32x4 x1 = *(const f32x4*)(ap + 4) + *(const f32x4*)(bp + 4);
  *(f32x4*)(resout + (size_t)tok * DMODEL + t * 8) = x0;
  *(f32x4*)(resout + (size_t)tok * DMODEL + t * 8 + 4) = x1;
  float ss = 0.f;
#pragma unroll
  for (int j = 0; j < 4; ++j) ss += x0[j] * x0[j] + x1[j] * x1[j];
#pragma unroll
  for (int m = 1; m < 64; m <<= 1) ss += __shfl_xor(ss, m, 64);
  __shared__ float red[4];
  if ((t & 63) == 0) red[t >> 6] = ss;
  __syncthreads();
  ss = red[0] + red[1] + red[2] + red[3];
  float sc = rsqrtf(ss * (1.f / (float)DMODEL) + 1e-6f);
  const float* wp = w + t * 8;
  float y[8];
#pragma unroll
  for (int j = 0; j < 4; ++j) {
    y[j] = x0[j] * sc * (1.f + wp[j]);
    y[4 + j] = x1[j] * sc * (1.f + wp[4 + j]);
  }
  u32x4 st;
  st[0] = pack2(y[0], y[1]);
  st[1] = pack2(y[2], y[3]);
  st[2] = pack2(y[4], y[5]);
  st[3] = pack2(y[6], y[7]);
  *(u32x4*)(hb + (size_t)tok * DMODEL + t * 8) = st;
}

// -------- bf16 MFMA GEMM: C[M,N] = A[M,K]_bf16 * Bt[N,K]^T ------------------
// BM=128, BN=256, BK=32; 4 waves, wave-tile 64x128 (4 A-frag + 8 B-frag -> 32
// MFMA per step, 2.67 MFMA per ds_read_b128). Ring-3 LDS (72KB, 2 blocks/CU),
// counted vmcnt(6/0) + raw s_barrier; stage-at-top (WAR barrier-protected).
// OUT: 0=f32 out (+ split-K slice per blockIdx.z), 1=bf16, 2=silu(Aux)*acc.
__device__ __forceinline__ void async16(const void* g, void* l) {
  __builtin_amdgcn_global_load_lds(
      (const __attribute__((address_space(1))) u32*)g,
      (__attribute__((address_space(3))) u32*)l, 16, 0, 0);
}

template <int OUT>
__global__ __launch_bounds__(256) void gemm_kernel(
    const u16* __restrict__ A, const u16* __restrict__ Bt,
    void* __restrict__ Cv, const u16* __restrict__ Aux, int M, int N,
    int Kfull, int Ks) {
  __shared__ __align__(16) u16 Al[3][128 * 32];
  __shared__ __align__(16) u16 Bl[3][256 * 32];
  int tid = threadIdx.x;
  int w = tid >> 6, l = tid & 63;
  int wr = w >> 1, wc = w & 1;
  int r15 = l & 15, kb = l >> 4;

  // ---- rasterization (x,y only; z = K-slice): XCD chunk + group-major GRP=4
  int nbx = gridDim.x, nby = gridDim.y;  // nbx = N/256, nby = M/128
  int bid = blockIdx.y * nbx + blockIdx.x;
  int nwg = nbx * nby;
  int cpx = nwg >> 3;
  int wg = (bid & 7) * cpx + (bid >> 3);
  const int GRP = 4;  // nbx % 4 == 0 in all launches (8,16,32)
  int span = GRP * nby;
  int grpId = wg / span;
  int rem = wg - grpId * span;
  int n0 = (grpId * GRP + (rem % GRP)) * 256;
  int m0 = (rem / GRP) * 128;
  int kbase = blockIdx.z * Ks;

  f32x4 acc[4][8] = {};

  auto stage = [&](int buf, int kt) {
#pragma unroll
    for (int c = 0; c < 2; ++c) {       // A: 512 granules, 2/thread
      int gid = c * 256 + tid;
      int row = gid >> 2;
      int g = (gid & 3) ^ ((row >> 1) & 3);
      async16(A + (size_t)(m0 + row) * Kfull + kt + g * 8, Al[buf] + gid * 8);
    }
#pragma unroll
    for (int c = 0; c < 4; ++c) {       // B: 1024 granules, 4/thread
      int gid = c * 256 + tid;
      int row = gid >> 2;
      int g = (gid & 3) ^ ((row >> 1) & 3);
      async16(Bt + (size_t)(n0 + row) * Kfull + kt + g * 8, Bl[buf] + gid * 8);
    }
  };

  int nst = Ks >> 5;
  stage(0, kbase);
  if (nst > 1) stage(1, kbase + 32);

  for (int i = 0; i < nst; ++i) {
    if (i + 1 < nst)
      asm volatile("s_waitcnt vmcnt(6)" ::: "memory");
    else
      asm volatile("s_waitcnt vmcnt(0)" ::: "memory");
    __builtin_amdgcn_s_barrier();  // buf i ready; prev-iter reads of buf (i+2)%3 done
    __builtin_amdgcn_sched_barrier(0);
    if (i + 2 < nst) stage((i + 2) % 3, kbase + (i + 2) * 32);
    const u16* Ac = Al[i % 3];
    const u16* Bc = Bl[i % 3];
    bf16x8 aF[4], bF[8];
#pragma unroll
    for (int m = 0; m < 4; ++m) {
      int row = wr * 64 + m * 16 + r15;
      aF[m] = *(const bf16x8*)(Ac + row * 32 + (kb ^ ((row >> 1) & 3)) * 8);
    }
#pragma unroll
    for (int n = 0; n < 8; ++n) {
      int row = wc * 128 + n * 16 + r15;
      bF[n] = *(const bf16x8*)(Bc + row * 32 + (kb ^ ((row >> 1) & 3)) * 8);
    }
#pragma unroll
    for (int m = 0; m < 4; ++m)
#pragma unroll
      for (int n = 0; n < 8; ++n)
        acc[m][n] = __builtin_amdgcn_mfma_f32_16x16x32_bf16(aF[m], bF[n],
                                                            acc[m][n], 0, 0, 0);
  }

  float* Cf = (float*)Cv + (size_t)blockIdx.z * M * N;  // split-K partial slice
#pragma unroll
  for (int m = 0; m < 4; ++m)
#pragma unroll
    for (int n = 0; n < 8; ++n) {
      size_t base = (size_t)(m0 + wr * 64 + m * 16 + kb * 4) * N +
                    (n0 + wc * 128 + n * 16 + r15);
#pragma unroll
      for (int r = 0; r < 4; ++r) {
        size_t idx = base + (size_t)r * N;
        if (OUT == 0)
          Cf[idx] = acc[m][n][r];
        else if (OUT == 1)
          ((u16*)Cv)[idx] = f2bf(acc[m][n][r]);
        else
          ((u16*)Cv)[idx] = f2bf(siluf(bf2f(Aux[idx])) * acc[m][n][r]);
      }
    }
}

// -------- split-K reduce: out[i] = sum_s parts[s*n + i] ---------------------
__global__ __launch_bounds__(256) void reduce_kernel(
    const float* __restrict__ p, float* __restrict__ o, int n, int S) {
  int i = (blockIdx.x * 256 + threadIdx.x) * 4;
  f32x4 s = *(const f32x4*)(p + i);
  for (int j = 1; j < S; ++j) s += *(const f32x4*)(p + (size_t)j * n + i);
  *(f32x4*)(o + i) = s;
}

// -------- ba = hb(bf16) @ Wba(f32 [2048,64]) --------------------------------
__global__ __launch_bounds__(256) void ba_gemm_kernel(
    const u16* __restrict__ hb, const float* __restrict__ Wba,
    float* __restrict__ ba) {
  int m = blockIdx.x;
  int t = threadIdx.x;
  int n = t & 63, kq = t >> 6;
  const u16* a = hb + (size_t)m * DMODEL + kq * 512;
  const float* wp = Wba + (size_t)kq * 512 * 64 + n;
  float sum = 0.f;
  for (int i = 0; i < 512; ++i)
    sum += bf2f(a[i]) * wp[(size_t)i * 64];
  __shared__ float red[256];
  red[t] = sum;
  __syncthreads();
  if (t < 64)
    ba[(size_t)m * 64 + t] = red[t] + red[t + 64] + red[t + 128] + red[t + 192];
}

// -------- causal depthwise conv (K=4) + SiLU, bf16 in/out -------------------
__global__ __launch_bounds__(256) void conv_silu_kernel(
    const u16* __restrict__ qkvb, const float* __restrict__ conv_w,
    u16* __restrict__ qkv) {
  int gid = blockIdx.x * 256 + threadIdx.x;  // BT * 2048 threads
  int c4 = (gid & 2047) * 4;
  int bt = gid >> 11;
  int b = bt >> 10, tt = bt & 1023;
  f32x4 wv[4];
#pragma unroll
  for (int j = 0; j < 4; ++j) wv[j] = *(const f32x4*)(conv_w + (c4 + j) * 4);
  float acc[4] = {0.f, 0.f, 0.f, 0.f};
#pragma unroll
  for (int i = 0; i < 4; ++i) {
    int ts = tt - 3 + i;
    if (ts >= 0) {
      u16x4 x = *(const u16x4*)(qkvb + (size_t)(b * 1024 + ts) * CONVC + c4);
#pragma unroll
      for (int j = 0; j < 4; ++j) acc[j] += bf2f(x[j]) * wv[j][i];
    }
  }
  u32x2 st;
  st[0] = pack2(siluf(acc[0]), siluf(acc[1]));
  st[1] = pack2(siluf(acc[2]), siluf(acc[3]));
  *(u32x2*)(qkv + (size_t)bt * CONVC + c4) = st;
}

// -------- l2 norm of q,k heads in place (bf16), q also * DK^-0.5 ------------
__global__ __launch_bounds__(256) void l2norm_kernel(u16* __restrict__ qkv) {
  int wid = blockIdx.x * 4 + (threadIdx.x >> 6);
  int l = threadIdx.x & 63;
  int tok = wid >> 5, slot = wid & 31;  // slot<16: q head, else k head
  u16* p = qkv + (size_t)tok * CONVC + slot * 128 + l * 2;
  float x0 = bf2f(p[0]), x1 = bf2f(p[1]);
  float ss = x0 * x0 + x1 * x1;
#pragma unroll
  for (int m = 1; m < 64; m <<= 1) ss += __shfl_xor(ss, m, 64);
  float sc = rsqrtf(ss + 1e-6f);
  if (slot < 16) sc *= 0.08838834764831845f;  // DK^-0.5
  *(u32*)p = pack2(x0 * sc, x1 * sc);
}

// -------- bd[(b*32+h)][t][2] = {sigmoid(bb), exp(-exp(A_log)*softplus)} -----
__global__ __launch_bounds__(256) void betadecay_kernel(
    const float* __restrict__ ba, const float* __restrict__ A_log,
    const float* __restrict__ dt_bias, float* __restrict__ bd) {
  int idx = blockIdx.x * 256 + threadIdx.x;  // BT*HV
  int h = idx & 31;
  int tok = idx >> 5;
  int b = tok >> 10, tt = tok & 1023;
  float bb = ba[(size_t)tok * 64 + h];
  float aa = ba[(size_t)tok * 64 + 32 + h];
  float bet = 1.f / (1.f + expf(-bb));
  float x = aa + dt_bias[h];
  float sp = (x > 20.f) ? x : log1pf(expf(x));
  float dec = expf(-expf(A_log[h]) * sp);
  size_t o = (((size_t)(b * 32 + h)) * 1024 + tt) * 2;
  bd[o] = bet;
  bd[o + 1] = dec;
}

// ======================= chunked delta-rule scan ============================
__global__ __launch_bounds__(256) void prep_kernel(
    const u16* __restrict__ qkvc, const float* __restrict__ bdpack,
    u16* __restrict__ Tg, u16* __restrict__ Pg, u16* __restrict__ KtTg,
    float* __restrict__ Bvec) {
  __shared__ __align__(16) u16 Kl[64 * 128];
  __shared__ __align__(16) u16 Ql[64 * 128];
  __shared__ __align__(16) float Af[64 * 64];
  __shared__ __align__(16) float Tf[64 * 64];
  __shared__ float lgl[64], bl[64], betal[64];
  int tid = threadIdx.x;
  int w = tid >> 6, l = tid & 63;
  int r15 = l & 15, kb = l >> 4;
  int c = blockIdx.x, bh = blockIdx.y;
  int b = bh >> 5, h = bh & 31, hk = h >> 1;
  size_t tok0 = (size_t)b * 1024 + c * 64;
  int ch = bh * 16 + c;  // chunk-head index

  // stage K, Q tiles [64][128] bf16
#pragma unroll
  for (int rep = 0; rep < 4; ++rep) {
    int gid = w * 256 + rep * 64 + l;
    int row = gid >> 4, seg = gid & 15;
    const u16* srcq = qkvc + (tok0 + row) * CONVC + hk * 128 + seg * 8;
    async16(srcq, Ql + gid * 8);
    async16(srcq + KEYDIM, Kl + gid * 8);
  }
  if (tid < 64) {
    size_t o = ((size_t)bh * 1024 + c * 64 + tid) * 2;
    betal[tid] = bdpack[o];
    lgl[tid] = logf(fmaxf(bdpack[o + 1], 1e-30f));
  }
  __syncthreads();
  if (tid < 64) {
    float s = 0.f;
    for (int j = 0; j <= tid; ++j) s += lgl[j];
    bl[tid] = s;
    Bvec[(size_t)ch * 64 + tid] = expf(s);
  }
  __syncthreads();

  // KK^T -> A (f32 LDS, strict lower, scaled); QK^T -> P (bf16 global)
  {
    f32x4 akk[4] = {}, aqk[4] = {};
#pragma unroll
    for (int ks = 0; ks < 4; ++ks) {
      bf16x8 kaF = *(const bf16x8*)(Kl + (w * 16 + r15) * 128 + ks * 32 + kb * 8);
      bf16x8 qaF = *(const bf16x8*)(Ql + (w * 16 + r15) * 128 + ks * 32 + kb * 8);
#pragma unroll
      for (int n = 0; n < 4; ++n) {
        bf16x8 bF = *(const bf16x8*)(Kl + (n * 16 + r15) * 128 + ks * 32 + kb * 8);
        akk[n] = __builtin_amdgcn_mfma_f32_16x16x32_bf16(kaF, bF, akk[n], 0, 0, 0);
        aqk[n] = __builtin_amdgcn_mfma_f32_16x16x32_bf16(qaF, bF, aqk[n], 0, 0, 0);
      }
    }
#pragma unroll
    for (int n = 0; n < 4; ++n)
#pragma unroll
      for (int r = 0; r < 4; ++r) {
        int i = w * 16 + kb * 4 + r;
        int j = n * 16 + r15;
        float e = expf(bl[i] - bl[j]);  // only used when j<=i (<=0 exponent)
        Af[i * 64 + j] = (j < i) ? betal[i] * e * akk[n][r] : 0.f;
        u16 pv = (j <= i) ? f2bf(e * aqk[n][r]) : (u16)0;
        Pg[(size_t)ch * 4096 + i * 64 + j] = pv;
      }
  }
  // KtT[d][j] = exp(b63-b_j) * K[j][d]  (bf16 global [128][64])
  float b63 = bl[63];
  for (int m = 0; m < 32; ++m) {
    int idx = tid * 32 + m;
    int d = idx >> 6, j = idx & 63;
    float v = bf2f(Kl[j * 128 + d]) * expf(b63 - bl[j]);
    KtTg[(size_t)ch * 8192 + idx] = f2bf(v);
  }
  __syncthreads();
  // T = I
#pragma unroll
  for (int m = 0; m < 16; ++m) Tf[tid * 16 + m] = 0.f;
  __syncthreads();
  if (tid < 64) Tf[tid * 65] = 1.f;
  __syncthreads();
  // forward substitution: wave w owns 16 columns, 4-way k-partials per column
  {
    int ccol = w * 16 + r15;
    int p = kb;
    for (int i = 1; i < 64; ++i) {
      float part = 0.f;
      for (int j = p; j < i; j += 4) part += Af[i * 64 + j] * Tf[j * 64 + ccol];
      part += __shfl_xor(part, 16, 64);
      part += __shfl_xor(part, 32, 64);
      if (p == 0) Tf[i * 64 + ccol] = ((ccol == i) ? 1.f : 0.f) - part;
    }
  }
  __syncthreads();
#pragma unroll
  for (int m = 0; m < 16; ++m) {
    int idx = tid * 16 + m;
    Tg[(size_t)ch * 4096 + idx] = f2bf(Tf[idx]);
  }
}

__global__ __launch_bounds__(512) void chunk_scan_kernel(
    const u16* __restrict__ qkvc, const float* __restrict__ bdpack,
    const u16* __restrict__ Tg, const u16* __restrict__ Pg,
    const u16* __restrict__ KtTg, const float* __restrict__ Bvec,
    u16* __restrict__ obf) {
  __shared__ __align__(16) u16 Kl[64 * 128];
  __shared__ __align__(16) u16 Ql[64 * 128];
  __shared__ __align__(16) u16 KtTl[128 * 64];
  __shared__ __align__(16) u16 Tl[64 * 64];
  __shared__ __align__(16) u16 Pl[64 * 64];
  __shared__ __align__(16) u16 Vl[64 * 32];
  __shared__ __align__(16) u16 St[32 * 128];
  __shared__ __align__(16) u16 rhsT[32 * 64];
  __shared__ __align__(16) u16 dT[32 * 64];
  __shared__ float betal[64], Gl[64];

  int tid = threadIdx.x;
  int w = tid >> 6, l = tid & 63;
  int r15 = l & 15, kb = l >> 4;
  int dvc = blockIdx.x, bh = blockIdx.y;
  int b = bh >> 5, h = bh & 31, hk = h >> 1;
  int a = w >> 1, bcol = w & 1;  // [64x32]-output tile: rows a*16.., cols bcol*16..

  for (int m = tid; m < 32 * 128; m += 512) St[m] = 0;
  f32x4 sAcc0 = {}, sAcc1 = {};
  __syncthreads();

  for (int c = 0; c < 16; ++c) {
    size_t tok0 = (size_t)b * 1024 + c * 64;
    int ch = bh * 16 + c;
    // ---- stage ----
#pragma unroll
    for (int rep = 0; rep < 2; ++rep) {
      int gid = w * 128 + rep * 64 + l;
      int row = gid >> 4, seg = gid & 15;
      const u16* srcq = qkvc + (tok0 + row) * CONVC + hk * 128 + seg * 8;
      async16(srcq, Ql + gid * 8);
      async16(srcq + KEYDIM, Kl + gid * 8);
      async16(KtTg + (size_t)ch * 8192 + gid * 8, KtTl + gid * 8);
    }
    {
      int gid = w * 64 + l;
      async16(Tg + (size_t)ch * 4096 + gid * 8, Tl + gid * 8);
      async16(Pg + (size_t)ch * 4096 + gid * 8, Pl + gid * 8);
    }
    if (w < 4) {
      int gid = w * 64 + l;  // 256 granules
      int row = gid >> 2, seg = gid & 3;
      async16(qkvc + (tok0 + row) * CONVC + 2 * KEYDIM + h * 128 + dvc * 32 + seg * 8,
              Vl + gid * 8);
    }
    if (tid < 64) {
      betal[tid] = bdpack[((size_t)bh * 1024 + c * 64 + tid) * 2];
      Gl[tid] = Bvec[(size_t)ch * 64 + tid];
    }
    __syncthreads();

    // ---- KS0 = K@S0, QS0 = Q@S0 ----
    f32x4 aKS = {}, aQS = {};
#pragma unroll
    for (int ks = 0; ks < 4; ++ks) {
      bf16x8 bF = *(const bf16x8*)(St + (bcol * 16 + r15) * 128 + ks * 32 + kb * 8);
      bf16x8 kF = *(const bf16x8*)(Kl + (a * 16 + r15) * 128 + ks * 32 + kb * 8);
      bf16x8 qF = *(const bf16x8*)(Ql + (a * 16 + r15) * 128 + ks * 32 + kb * 8);
      aKS = __builtin_amdgcn_mfma_f32_16x16x32_bf16(kF, bF, aKS, 0, 0, 0);
      aQS = __builtin_amdgcn_mfma_f32_16x16x32_bf16(qF, bF, aQS, 0, 0, 0);
    }
    // ---- rhsT[dv][i] = beta_i (v - B_i * KS0) ----
    {
      int i0 = a * 16 + kb * 4;
      int dv = bcol * 16 + r15;
      u16x4 st;
#pragma unroll
      for (int r = 0; r < 4; ++r) {
        int i = i0 + r;
        float v = bf2f(Vl[i * 32 + dv]);
        st[r] = f2bf(betal[i] * (v - Gl[i] * aKS[r]));
      }
      *(u16x4*)(rhsT + dv * 64 + i0) = st;
    }
    __syncthreads();
    // ---- delta = T @ rhs ----
    f32x4 aD = {};
#pragma unroll
    for (int ks = 0; ks < 2; ++ks) {
      bf16x8 aF = *(const bf16x8*)(Tl + (a * 16 + r15) * 64 + ks * 32 + kb * 8);
      bf16x8 bF = *(const bf16x8*)(rhsT + (bcol * 16 + r15) * 64 + ks * 32 + kb * 8);
      aD = __builtin_amdgcn_mfma_f32_16x16x32_bf16(aF, bF, aD, 0, 0, 0);
    }
    {
      int i0 = a * 16 + kb * 4;
      int dv = bcol * 16 + r15;
      u16x4 st;
#pragma unroll
      for (int r = 0; r < 4; ++r) st[r] = f2bf(aD[r]);
      *(u16x4*)(dT + dv * 64 + i0) = st;
    }
    __syncthreads();
    // ---- O = B.*QS0 + P @ delta -> global ----
    f32x4 aO = {};
#pragma unroll
    for (int ks = 0; ks < 2; ++ks) {
      bf16x8 aF = *(const bf16x8*)(Pl + (a * 16 + r15) * 64 + ks * 32 + kb * 8);
      bf16x8 bF = *(const bf16x8*)(dT + (bcol * 16 + r15) * 64 + ks * 32 + kb * 8);
      aO = __builtin_amdgcn_mfma_f32_16x16x32_bf16(aF, bF, aO, 0, 0, 0);
    }
    {
      int i0 = a * 16 + kb * 4;
      int dv = bcol * 16 + r15;
#pragma unroll
      for (int r = 0; r < 4; ++r) {
        int i = i0 + r;
        float o = aO[r] + Gl[i] * aQS[r];
        obf[(tok0 + i) * VALDIM + h * 128 + dvc * 32 + dv] = f2bf(o);
      }
    }
    // ---- state update: S = B63*S + KtT @ delta ----
    float gL = Gl[63];
#pragma unroll
    for (int r = 0; r < 4; ++r) { sAcc0[r] *= gL; sAcc1[r] *= gL; }
#pragma unroll
    for (int ks = 0; ks < 2; ++ks) {
      bf16x8 aF = *(const bf16x8*)(KtTl + (w * 16 + r15) * 64 + ks * 32 + kb * 8);
      bf16x8 b0 = *(const bf16x8*)(dT + r15 * 64 + ks * 32 + kb * 8);
      bf16x8 b1 = *(const bf16x8*)(dT + (16 + r15) * 64 + ks * 32 + kb * 8);
      sAcc0 = __builtin_amdgcn_mfma_f32_16x16x32_bf16(aF, b0, sAcc0, 0, 0, 0);
      sAcc1 = __builtin_amdgcn_mfma_f32_16x16x32_bf16(aF, b1, sAcc1, 0, 0, 0);
    }
#pragma unroll
    for (int r = 0; r < 4; ++r) {
      int dk = w * 16 + kb * 4 + r;
      St[r15 * 128 + dk] = f2bf(sAcc0[r]);
      St[(16 + r15) * 128 + dk] = f2bf(sAcc1[r]);
    }
    __syncthreads();
  }
}

// -------- gate (silu(z)) + per-head RMSNorm, in-place over z ----------------
__global__ __launch_bounds__(256) void gatenorm_kernel(
    const u16* __restrict__ obf, u16* __restrict__ zb,
    const float* __restrict__ norm_w) {
  int wid = blockIdx.x * 4 + (threadIdx.x >> 6);
  int l = threadIdx.x & 63;
  int tok = wid >> 5, h = wid & 31;
  const u16* op = obf + (size_t)tok * VALDIM + h * 128 + l * 2;
  u16* zp = zb + (size_t)tok * VALDIM + h * 128 + l * 2;
  float o0 = bf2f(op[0]), o1 = bf2f(op[1]);
  float z0 = bf2f(zp[0]), z1 = bf2f(zp[1]);
  float g0 = o0 * siluf(z0);
  float g1 = o1 * siluf(z1);
  float ss = g0 * g0 + g1 * g1;
#pragma unroll
  for (int m = 1; m < 64; m <<= 1) ss += __shfl_xor(ss, m, 64);
  float sc = rsqrtf(ss * (1.f / 128.f) + 1e-6f);
  int e = l * 2;
  *(u32*)zp = pack2(g0 * sc * norm_w[e], g1 * sc * norm_w[e + 1]);
}

// -------- diagnostic: encode ws_size into d_out[0] --------------------------
__global__ void diag_kernel(float* out, float val) { out[0] = val; }

extern "C" void kernel_launch(void* const* d_in, const int* in_sizes, int n_in,
                              void* d_out, int out_size, void* d_ws,
                              size_t ws_size, hipStream_t stream) {
  const float* hidden = (const float*)d_in[1];
  const float* residual = (const float*)d_in[2];
  const float* ln_in_w = (const float*)d_in[3];
  const float* ln_post_w = (const float*)d_in[4];
  const float* Wqkvz = (const float*)d_in[5];
  const float* Wba = (const float*)d_in[6];
  const float* conv_w = (const float*)d_in[7];
  const float* A_log = (const float*)d_in[8];
  const float* dt_bias = (const float*)d_in[9];
  const float* norm_w = (const float*)d_in[10];
  const float* Wout = (const float*)d_in[11];
  const float* Wgate = (const float*)d_in[12];
  const float* Wup = (const float*)d_in[13];
  const float* Wdown = (const float*)d_in[14];

  char* ws = (char*)d_ws;
  size_t off = 0;
  auto alloc = [&](size_t n) {
    char* p = ws + off;
    off = (off + n + 255) & ~(size_t)255;
    return p;
  };
  u16* wslot = (u16*)alloc((size_t)INTER * DMODEL * 2);       // 33.55 MB
  u16* hb = (u16*)alloc((size_t)BT * DMODEL * 2);             //  8.39 MB
  u16* qkvb = (u16*)alloc((size_t)BT * CONVC * 2);            // 33.55 MB
  u16* zb = (u16*)alloc((size_t)BT * VALDIM * 2);             // 16.78 MB
  u16* qkvc = (u16*)alloc((size_t)BT * CONVC * 2);            // 33.55 MB
  float* ba = (float*)alloc((size_t)BT * 64 * 4);             //  0.52 MB
  float* bdpack = (float*)alloc((size_t)64 * 1024 * 2 * 4);   //  0.52 MB
  u16* obf = (u16*)alloc((size_t)BT * VALDIM * 2);            // 16.78 MB
  if (off > ws_size) {                                        // ~143.7 MB total
    diag_kernel<<<1, 1, 0, stream>>>((float*)d_out, (float)(ws_size >> 20));
    return;
  }

  float* res1 = (float*)d_out;                        // part1 (dead before out)
  float* attn = (float*)d_out + (size_t)BT * DMODEL;  // part2
  float* res2 = attn;                                 // in-place
  u16* h2b = hb;                                      // hb dead after GEMM1/ba
  u16* gbuf = qkvc;                                   // qkvc dead after scan
  u16* mbuf = qkvb;                                   // up GEMM writes m directly
  float* outp = (float*)d_out;                        // final (res1 dead)

  // chunked-scan prep outputs live in dead qkvb (exact fit) + ba regions
  u16* Tg = qkvb;                                     // 1024 x 4096 u16
  u16* Pg = qkvb + (size_t)1024 * 4096;               // 1024 x 4096 u16
  u16* KtTg = qkvb + (size_t)2 * 1024 * 4096;         // 1024 x 8192 u16
  float* Bvec = ba;                                   // 1024 x 64 f32

  // split-K partials (dead-region reuse):
  float* pWout = (float*)qkvb;  // 2 x 2048x2048 f32 = 33.55 MB (qkvb dead)
  float* pDown = (float*)zb;    // 4 x 2048x2048 f32 = 67.1 MB (zb..obf dead)

  dim3 blk(256);

  // 1. res1 = hidden+residual; hb = rmsnorm(res1)
  resnorm_kernel<<<BT, blk, 0, stream>>>(hidden, residual, ln_in_w, res1, hb);

  // 2. qkv-slice GEMM: qkvb = hb @ Wqkvz[:, :8192]
  convert_transpose<<<dim3(CONVC / 32, DMODEL / 32), blk, 0, stream>>>(
      Wqkvz, QKVZ_N, wslot, DMODEL, CONVC);
  gemm_kernel<1><<<dim3(CONVC / 256, BT / 128), blk, 0, stream>>>(
      hb, wslot, qkvb, nullptr, BT, CONVC, DMODEL, DMODEL);

  // 3. z-slice GEMM: zb = hb @ Wqkvz[:, 8192:]
  convert_transpose<<<dim3(VALDIM / 32, DMODEL / 32), blk, 0, stream>>>(
      Wqkvz + CONVC, QKVZ_N, wslot, DMODEL, VALDIM);
  gemm_kernel<1><<<dim3(VALDIM / 256, BT / 128), blk, 0, stream>>>(
      hb, wslot, zb, nullptr, BT, VALDIM, DMODEL, DMODEL);

  // 4. ba = hb @ Wba
  ba_gemm_kernel<<<BT, blk, 0, stream>>>(hb, Wba, ba);

  // 5-7. conv+silu, l2norm(q,k), beta/decay (packed per-head layout)
  conv_silu_kernel<<<BT * 2048 / 256, blk, 0, stream>>>(qkvb, conv_w, qkvc);
  l2norm_kernel<<<BT * 32 / 4, blk, 0, stream>>>(qkvc);
  betadecay_kernel<<<BT * HV / 256, blk, 0, stream>>>(ba, A_log, dt_bias,
                                                      bdpack);

  // 8. chunked gated delta rule scan (prep parallel, then sequential-in-chunk)
  prep_kernel<<<dim3(16, 64), blk, 0, stream>>>(qkvc, bdpack, Tg, Pg, KtTg,
                                                Bvec);
  chunk_scan_kernel<<<dim3(4, 64), dim3(512), 0, stream>>>(
      qkvc, bdpack, Tg, Pg, KtTg, Bvec, obf);

  // 9. gate + per-head RMSNorm (in place over zb)
  gatenorm_kernel<<<BT * HV / 4, blk, 0, stream>>>(obf, zb, norm_w);

  // 10. attn = og @ Wout  (split-K=2 partials in dead qkvb, reduce to attn)
  convert_transpose<<<dim3(DMODEL / 32, VALDIM / 32), blk, 0, stream>>>(
      Wout, DMODEL, wslot, VALDIM, DMODEL);
  gemm_kernel<0><<<dim3(DMODEL / 256, BT / 128, 2), blk, 0, stream>>>(
      zb, wslot, pWout, nullptr, BT, DMODEL, VALDIM, VALDIM / 2);
  reduce_kernel<<<BT * DMODEL / 1024, blk, 0, stream>>>(pWout, attn,
                                                        BT * DMODEL, 2);

  // 11. res2 = attn + res1 (in place, part2); h2b = rmsnorm(res2)
  resnorm_kernel<<<BT, blk, 0, stream>>>(attn, res1, ln_post_w, res2, h2b);

  // 12. gate GEMM (bf16 out)
  convert_transpose<<<dim3(INTER / 32, DMODEL / 32), blk, 0, stream>>>(
      Wgate, INTER, wslot, DMODEL, INTER);
  gemm_kernel<1><<<dim3(INTER / 256, BT / 128), blk, 0, stream>>>(
      h2b, wslot, gbuf, nullptr, BT, INTER, DMODEL, DMODEL);

  // 13. up GEMM fused with m = silu(g)*u (writes mbuf directly)
  convert_transpose<<<dim3(INTER / 32, DMODEL / 32), blk, 0, stream>>>(
      Wup, INTER, wslot, DMODEL, INTER);
  gemm_kernel<2><<<dim3(INTER / 256, BT / 128), blk, 0, stream>>>(
      h2b, wslot, mbuf, gbuf, BT, INTER, DMODEL, DMODEL);

  // 14. out = m @ Wdown (split-K=4 partials in dead zb..obf, reduce to outp)
  convert_transpose<<<dim3(DMODEL / 32, INTER / 32), blk, 0, stream>>>(
      Wdown, DMODEL, wslot, INTER, DMODEL);
  gemm_kernel<0><<<dim3(DMODEL / 256, BT / 128, 4), blk, 0, stream>>>(
      mbuf, wslot, pDown, nullptr, BT, DMODEL, INTER, INTER / 4);
  reduce_kernel<<<BT * DMODEL / 1024, blk, 0, stream>>>(pDown, outp,
                                                        BT * DMODEL, 4);
}

// Round 10
// 875.252 us; speedup vs baseline: 1.1769x; 1.1769x over previous
//
#include <hip/hip_runtime.h>
#include <hip/hip_bf16.h>

typedef unsigned short u16;
typedef unsigned int u32;
typedef float f32x4 __attribute__((ext_vector_type(4)));
typedef short bf16x8 __attribute__((ext_vector_type(8)));
typedef unsigned short u16x4 __attribute__((ext_vector_type(4)));
typedef unsigned int u32x2 __attribute__((ext_vector_type(2)));
typedef unsigned int u32x4 __attribute__((ext_vector_type(4)));

#define BT 2048            // B*T
#define DMODEL 2048
#define HV 32
#define DK 128
#define KEYDIM 2048
#define VALDIM 4096
#define QKVZ_N 12288
#define CONVC 8192         // q,k,v channels
#define INTER 8192

__device__ __forceinline__ float bf2f(u16 v) {
  u32 u = ((u32)v) << 16;
  return __builtin_bit_cast(float, u);
}
__device__ __forceinline__ u16 f2bf(float f) {
  u32 u = __builtin_bit_cast(u32, f);
  u32 r = (u + 0x7fffu + ((u >> 16) & 1u)) >> 16;
  return (u16)r;
}
__device__ __forceinline__ u32 pack2(float a, float b) {
  return (u32)f2bf(a) | ((u32)f2bf(b) << 16);
}
__device__ __forceinline__ float siluf(float x) {
  return x / (1.f + expf(-x));
}

// -------- weight convert+transpose: W[K,N] f32 (row stride ldw) -> Wt[N,K] bf16
__global__ __launch_bounds__(256) void convert_transpose(
    const float* __restrict__ W, int ldw, u16* __restrict__ Wt, int K, int N) {
  __shared__ float tile[32][33];
  int n0 = blockIdx.x * 32, k0 = blockIdx.y * 32;
  int tx = threadIdx.x & 31, ty = threadIdx.x >> 5;  // ty 0..7
#pragma unroll
  for (int i = 0; i < 4; ++i) {
    int kk = ty + i * 8;
    tile[kk][tx] = W[(size_t)(k0 + kk) * ldw + n0 + tx];
  }
  __syncthreads();
#pragma unroll
  for (int i = 0; i < 4; ++i) {
    int nn = ty + i * 8;
    Wt[(size_t)(n0 + nn) * K + k0 + tx] = f2bf(tile[tx][nn]);
  }
}

// -------- fused residual add + gemma RMSNorm (a+b -> resout f32, norm -> bf16)
__global__ __launch_bounds__(256) void resnorm_kernel(
    const float* __restrict__ a, const float* __restrict__ b,
    const float* __restrict__ w, float* __restrict__ resout,
    u16* __restrict__ hb) {
  int tok = blockIdx.x, t = threadIdx.x;
  const float* ap = a + (size_t)tok * DMODEL + t * 8;
  const float* bp = b + (size_t)tok * DMODEL + t * 8;
  f32x4 x0 = *(const f32x4*)ap + *(const f32x4*)bp;
  f32x4 x1 = *(const f32x4*)(ap + 4) + *(const f32x4*)(bp + 4);
  *(f32x4*)(resout + (size_t)tok * DMODEL + t * 8) = x0;
  *(f32x4*)(resout + (size_t)tok * DMODEL + t * 8 + 4) = x1;
  float ss = 0.f;
#pragma unroll
  for (int j = 0; j < 4; ++j) ss += x0[j] * x0[j] + x1[j] * x1[j];
#pragma unroll
  for (int m = 1; m < 64; m <<= 1) ss += __shfl_xor(ss, m, 64);
  __shared__ float red[4];
  if ((t & 63) == 0) red[t >> 6] = ss;
  __syncthreads();
  ss = red[0] + red[1] + red[2] + red[3];
  float sc = rsqrtf(ss * (1.f / (float)DMODEL) + 1e-6f);
  const float* wp = w + t * 8;
  float y[8];
#pragma unroll
  for (int j = 0; j < 4; ++j) {
    y[j] = x0[j] * sc * (1.f + wp[j]);
    y[4 + j] = x1[j] * sc * (1.f + wp[4 + j]);
  }
  u32x4 st;
  st[0] = pack2(y[0], y[1]);
  st[1] = pack2(y[2], y[3]);
  st[2] = pack2(y[4], y[5]);
  st[3] = pack2(y[6], y[7]);
  *(u32x4*)(hb + (size_t)tok * DMODEL + t * 8) = st;
}

__device__ __forceinline__ void async16(const void* g, void* l) {
  __builtin_amdgcn_global_load_lds(
      (const __attribute__((address_space(1))) u32*)g,
      (__attribute__((address_space(3))) u32*)l, 16, 0, 0);
}

// -------- 128-tile MFMA GEMM (proven round-8): ring-4, counted vmcnt --------
template <int OUT>
__global__ __launch_bounds__(256) void gemm_kernel(
    const u16* __restrict__ A, const u16* __restrict__ Bt,
    void* __restrict__ Cv, const u16* __restrict__ Aux, int M, int N,
    int Kfull, int Ks) {
  __shared__ __align__(16) u16 Al[4][128 * 32];
  __shared__ __align__(16) u16 Bl[4][128 * 32];
  int tid = threadIdx.x;
  int w = tid >> 6, l = tid & 63;
  int wr = w >> 1, wc = w & 1;
  int r15 = l & 15, kb = l >> 4;

  int nbx = gridDim.x, nby = gridDim.y;
  int bid = blockIdx.y * nbx + blockIdx.x;
  int nwg = nbx * nby;
  int cpx = nwg >> 3;
  int wg = (bid & 7) * cpx + (bid >> 3);
  const int GRP = 4;
  int span = GRP * nby;
  int grpId = wg / span;
  int rem = wg - grpId * span;
  int n0 = (grpId * GRP + (rem % GRP)) * 128;
  int m0 = (rem / GRP) * 128;
  int kbase = blockIdx.z * Ks;

  f32x4 acc[4][4] = {};

  auto stage = [&](int buf, int kt) {
#pragma unroll
    for (int c = 0; c < 2; ++c) {
      int gid = w * 128 + c * 64 + l;
      int row = gid >> 2;
      int g = (gid & 3) ^ ((row >> 1) & 3);
      async16(A + (size_t)(m0 + row) * Kfull + kt + g * 8, Al[buf] + gid * 8);
      async16(Bt + (size_t)(n0 + row) * Kfull + kt + g * 8, Bl[buf] + gid * 8);
    }
  };

  int nst = Ks >> 5;
#pragma unroll
  for (int p = 0; p < 3; ++p)
    if (p < nst) stage(p & 3, kbase + p * 32);

  for (int i = 0; i < nst; ++i) {
    int issued = (i + 3 < nst) ? (i + 3) : nst;
    int infl = issued - i - 1;
    if (infl >= 2)
      asm volatile("s_waitcnt vmcnt(8)" ::: "memory");
    else if (infl == 1)
      asm volatile("s_waitcnt vmcnt(4)" ::: "memory");
    else
      asm volatile("s_waitcnt vmcnt(0)" ::: "memory");
    __builtin_amdgcn_s_barrier();
    __builtin_amdgcn_sched_barrier(0);
    if (i + 3 < nst) stage((i + 3) & 3, kbase + (i + 3) * 32);
    const u16* Ac = Al[i & 3];
    const u16* Bc = Bl[i & 3];
    bf16x8 aF[4], bF[4];
#pragma unroll
    for (int m = 0; m < 4; ++m) {
      int row = wr * 64 + m * 16 + r15;
      aF[m] = *(const bf16x8*)(Ac + row * 32 + (kb ^ ((row >> 1) & 3)) * 8);
    }
#pragma unroll
    for (int n = 0; n < 4; ++n) {
      int row = wc * 64 + n * 16 + r15;
      bF[n] = *(const bf16x8*)(Bc + row * 32 + (kb ^ ((row >> 1) & 3)) * 8);
    }
#pragma unroll
    for (int m = 0; m < 4; ++m)
#pragma unroll
      for (int n = 0; n < 4; ++n)
        acc[m][n] = __builtin_amdgcn_mfma_f32_16x16x32_bf16(aF[m], bF[n],
                                                            acc[m][n], 0, 0, 0);
  }

  float* Cf = (float*)Cv + (size_t)blockIdx.z * M * N;
#pragma unroll
  for (int m = 0; m < 4; ++m)
#pragma unroll
    for (int n = 0; n < 4; ++n) {
      size_t base = (size_t)(m0 + wr * 64 + m * 16 + kb * 4) * N +
                    (n0 + wc * 64 + n * 16 + r15);
#pragma unroll
      for (int r = 0; r < 4; ++r) {
        size_t idx = base + (size_t)r * N;
        if (OUT == 0)
          Cf[idx] = acc[m][n][r];
        else if (OUT == 1)
          ((u16*)Cv)[idx] = f2bf(acc[m][n][r]);
        else
          ((u16*)Cv)[idx] = f2bf(siluf(bf2f(Aux[idx])) * acc[m][n][r]);
      }
    }
}

// -------- 256-tile deep-pipeline GEMM (8-phase-style, BK=64, 512 thr) -------
// 2 phases/K-tile: vmcnt(4); barrier; stage k-half of t+1; 12 ds_read; 32 MFMA.
// Steady state: 8 loads in flight, full-tile prefetch distance; vmcnt(0) only
// at the very last phase. 2-way LDS banking via key=(row^(row>>2))&3.
template <int OUT>
__global__ __launch_bounds__(512, 2) void gemm256_kernel(
    const u16* __restrict__ A, const u16* __restrict__ Bt,
    void* __restrict__ Cv, const u16* __restrict__ Aux, int M, int N,
    int Kfull, int Ks) {
  __shared__ __align__(16) u16 Asm[2 * 2 * 8192];  // [buf][kh][256][32]
  __shared__ __align__(16) u16 Bsm[2 * 2 * 8192];
  int tid = threadIdx.x;
  int w = tid >> 6, l = tid & 63;
  int wm = w >> 2, wn = w & 3;     // 2 x 4 waves; wave tile 128(M) x 64(N)
  int r15 = l & 15, kb = l >> 4;

  int nbx = gridDim.x, nby = gridDim.y;  // N/256, M/256
  int bid = blockIdx.y * nbx + blockIdx.x;
  int nwg = nbx * nby;
  int cpx = nwg >> 3;
  int wg = (bid & 7) * cpx + (bid >> 3);
  const int GRP = 4;
  int span = GRP * nby;
  int grpId = wg / span;
  int rem = wg - grpId * span;
  int n0 = (grpId * GRP + (rem % GRP)) * 256;
  int m0 = (rem / GRP) * 256;
  int kbase = blockIdx.z * Ks;

  f32x4 acc[8][4] = {};

  // stage one k-half (32 cols) of tile kt into buf: A 2 + B 2 loads/thread
  auto stage_kh = [&](int buf, int ktElem, int kh) {
#pragma unroll
    for (int c = 0; c < 2; ++c) {
      int gid = c * 512 + tid;  // 1024 granules = 256 rows x 4
      int row = gid >> 2, gg = gid & 3;
      int gl = gg ^ ((row ^ (row >> 2)) & 3);
      async16(A + (size_t)(m0 + row) * Kfull + ktElem + kh * 32 + gl * 8,
              Asm + (buf * 16384 + kh * 8192 + gid * 8));
    }
#pragma unroll
    for (int c = 0; c < 2; ++c) {
      int gid = c * 512 + tid;
      int row = gid >> 2, gg = gid & 3;
      int gl = gg ^ ((row ^ (row >> 2)) & 3);
      async16(Bt + (size_t)(n0 + row) * Kfull + ktElem + kh * 32 + gl * 8,
              Bsm + (buf * 16384 + kh * 8192 + gid * 8));
    }
  };

  int nt = Ks >> 6;  // K-tiles of 64
  stage_kh(0, kbase, 0);
  stage_kh(0, kbase, 1);

  for (int t = 0; t < nt; ++t) {
    int buf = t & 1;
    bool pf = (t + 1 < nt);
    int nktElem = kbase + (t + 1) * 64;
#pragma unroll
    for (int ks = 0; ks < 2; ++ks) {
      if (ks == 0 || pf)
        asm volatile("s_waitcnt vmcnt(4)" ::: "memory");
      else
        asm volatile("s_waitcnt vmcnt(0)" ::: "memory");
      __builtin_amdgcn_s_barrier();
      __builtin_amdgcn_sched_barrier(0);
      if (pf) stage_kh(buf ^ 1, nktElem, ks);
      const u16* Ac = Asm + (buf * 16384 + ks * 8192);
      const u16* Bc = Bsm + (buf * 16384 + ks * 8192);
      bf16x8 aF[8], bF[4];
#pragma unroll
      for (int m = 0; m < 8; ++m) {
        int row = wm * 128 + m * 16 + r15;
        aF[m] = *(const bf16x8*)(Ac + row * 32 +
                                 ((kb ^ ((row ^ (row >> 2)) & 3)) * 8));
      }
#pragma unroll
      for (int n = 0; n < 4; ++n) {
        int row = wn * 64 + n * 16 + r15;
        bF[n] = *(const bf16x8*)(Bc + row * 32 +
                                 ((kb ^ ((row ^ (row >> 2)) & 3)) * 8));
      }
      __builtin_amdgcn_s_setprio(1);
#pragma unroll
      for (int m = 0; m < 8; ++m)
#pragma unroll
        for (int n = 0; n < 4; ++n)
          acc[m][n] = __builtin_amdgcn_mfma_f32_16x16x32_bf16(
              aF[m], bF[n], acc[m][n], 0, 0, 0);
      __builtin_amdgcn_s_setprio(0);
    }
  }

  float* Cf = (float*)Cv + (size_t)blockIdx.z * M * N;
#pragma unroll
  for (int m = 0; m < 8; ++m)
#pragma unroll
    for (int n = 0; n < 4; ++n) {
      size_t base = (size_t)(m0 + wm * 128 + m * 16 + kb * 4) * N +
                    (n0 + wn * 64 + n * 16 + r15);
#pragma unroll
      for (int r = 0; r < 4; ++r) {
        size_t idx = base + (size_t)r * N;
        if (OUT == 0)
          Cf[idx] = acc[m][n][r];
        else if (OUT == 1)
          ((u16*)Cv)[idx] = f2bf(acc[m][n][r]);
        else
          ((u16*)Cv)[idx] = f2bf(siluf(bf2f(Aux[idx])) * acc[m][n][r]);
      }
    }
}

// -------- split-K reduce: out[i] = sum_s parts[s*n + i] ---------------------
__global__ __launch_bounds__(256) void reduce_kernel(
    const float* __restrict__ p, float* __restrict__ o, int n, int S) {
  int i = (blockIdx.x * 256 + threadIdx.x) * 4;
  f32x4 s = *(const f32x4*)(p + i);
  for (int j = 1; j < S; ++j) s += *(const f32x4*)(p + (size_t)j * n + i);
  *(f32x4*)(o + i) = s;
}

// -------- ba = hb(bf16) @ Wba(f32 [2048,64]) --------------------------------
__global__ __launch_bounds__(256) void ba_gemm_kernel(
    const u16* __restrict__ hb, const float* __restrict__ Wba,
    float* __restrict__ ba) {
  int m = blockIdx.x;
  int t = threadIdx.x;
  int n = t & 63, kq = t >> 6;
  const u16* a = hb + (size_t)m * DMODEL + kq * 512;
  const float* wp = Wba + (size_t)kq * 512 * 64 + n;
  float sum = 0.f;
  for (int i = 0; i < 512; ++i)
    sum += bf2f(a[i]) * wp[(size_t)i * 64];
  __shared__ float red[256];
  red[t] = sum;
  __syncthreads();
  if (t < 64)
    ba[(size_t)m * 64 + t] = red[t] + red[t + 64] + red[t + 128] + red[t + 192];
}

// -------- causal depthwise conv (K=4) + SiLU, bf16 in/out -------------------
__global__ __launch_bounds__(256) void conv_silu_kernel(
    const u16* __restrict__ qkvb, const float* __restrict__ conv_w,
    u16* __restrict__ qkv) {
  int gid = blockIdx.x * 256 + threadIdx.x;
  int c4 = (gid & 2047) * 4;
  int bt = gid >> 11;
  int b = bt >> 10, tt = bt & 1023;
  f32x4 wv[4];
#pragma unroll
  for (int j = 0; j < 4; ++j) wv[j] = *(const f32x4*)(conv_w + (c4 + j) * 4);
  float acc[4] = {0.f, 0.f, 0.f, 0.f};
#pragma unroll
  for (int i = 0; i < 4; ++i) {
    int ts = tt - 3 + i;
    if (ts >= 0) {
      u16x4 x = *(const u16x4*)(qkvb + (size_t)(b * 1024 + ts) * CONVC + c4);
#pragma unroll
      for (int j = 0; j < 4; ++j) acc[j] += bf2f(x[j]) * wv[j][i];
    }
  }
  u32x2 st;
  st[0] = pack2(siluf(acc[0]), siluf(acc[1]));
  st[1] = pack2(siluf(acc[2]), siluf(acc[3]));
  *(u32x2*)(qkv + (size_t)bt * CONVC + c4) = st;
}

// -------- l2 norm of q,k heads in place (bf16), q also * DK^-0.5 ------------
__global__ __launch_bounds__(256) void l2norm_kernel(u16* __restrict__ qkv) {
  int wid = blockIdx.x * 4 + (threadIdx.x >> 6);
  int l = threadIdx.x & 63;
  int tok = wid >> 5, slot = wid & 31;
  u16* p = qkv + (size_t)tok * CONVC + slot * 128 + l * 2;
  float x0 = bf2f(p[0]), x1 = bf2f(p[1]);
  float ss = x0 * x0 + x1 * x1;
#pragma unroll
  for (int m = 1; m < 64; m <<= 1) ss += __shfl_xor(ss, m, 64);
  float sc = rsqrtf(ss + 1e-6f);
  if (slot < 16) sc *= 0.08838834764831845f;  // DK^-0.5
  *(u32*)p = pack2(x0 * sc, x1 * sc);
}

// -------- bd[(b*32+h)][t][2] = {sigmoid(bb), exp(-exp(A_log)*softplus)} -----
__global__ __launch_bounds__(256) void betadecay_kernel(
    const float* __restrict__ ba, const float* __restrict__ A_log,
    const float* __restrict__ dt_bias, float* __restrict__ bd) {
  int idx = blockIdx.x * 256 + threadIdx.x;
  int h = idx & 31;
  int tok = idx >> 5;
  int b = tok >> 10, tt = tok & 1023;
  float bb = ba[(size_t)tok * 64 + h];
  float aa = ba[(size_t)tok * 64 + 32 + h];
  float bet = 1.f / (1.f + expf(-bb));
  float x = aa + dt_bias[h];
  float sp = (x > 20.f) ? x : log1pf(expf(x));
  float dec = expf(-expf(A_log[h]) * sp);
  size_t o = (((size_t)(b * 32 + h)) * 1024 + tt) * 2;
  bd[o] = bet;
  bd[o + 1] = dec;
}

// ======================= chunked delta-rule scan ============================
__global__ __launch_bounds__(256) void prep_kernel(
    const u16* __restrict__ qkvc, const float* __restrict__ bdpack,
    u16* __restrict__ Tg, u16* __restrict__ Pg, u16* __restrict__ KtTg,
    float* __restrict__ Bvec) {
  __shared__ __align__(16) u16 Kl[64 * 128];
  __shared__ __align__(16) u16 Ql[64 * 128];
  __shared__ __align__(16) float Af[64 * 64];
  __shared__ __align__(16) float Tf[64 * 64];
  __shared__ float lgl[64], bl[64], betal[64];
  int tid = threadIdx.x;
  int w = tid >> 6, l = tid & 63;
  int r15 = l & 15, kb = l >> 4;
  int c = blockIdx.x, bh = blockIdx.y;
  int b = bh >> 5, h = bh & 31, hk = h >> 1;
  size_t tok0 = (size_t)b * 1024 + c * 64;
  int ch = bh * 16 + c;

#pragma unroll
  for (int rep = 0; rep < 4; ++rep) {
    int gid = w * 256 + rep * 64 + l;
    int row = gid >> 4, seg = gid & 15;
    const u16* srcq = qkvc + (tok0 + row) * CONVC + hk * 128 + seg * 8;
    async16(srcq, Ql + gid * 8);
    async16(srcq + KEYDIM, Kl + gid * 8);
  }
  if (tid < 64) {
    size_t o = ((size_t)bh * 1024 + c * 64 + tid) * 2;
    betal[tid] = bdpack[o];
    lgl[tid] = logf(fmaxf(bdpack[o + 1], 1e-30f));
  }
  __syncthreads();
  if (tid < 64) {
    float s = 0.f;
    for (int j = 0; j <= tid; ++j) s += lgl[j];
    bl[tid] = s;
    Bvec[(size_t)ch * 64 + tid] = expf(s);
  }
  __syncthreads();

  {
    f32x4 akk[4] = {}, aqk[4] = {};
#pragma unroll
    for (int ks = 0; ks < 4; ++ks) {
      bf16x8 kaF = *(const bf16x8*)(Kl + (w * 16 + r15) * 128 + ks * 32 + kb * 8);
      bf16x8 qaF = *(const bf16x8*)(Ql + (w * 16 + r15) * 128 + ks * 32 + kb * 8);
#pragma unroll
      for (int n = 0; n < 4; ++n) {
        bf16x8 bF = *(const bf16x8*)(Kl + (n * 16 + r15) * 128 + ks * 32 + kb * 8);
        akk[n] = __builtin_amdgcn_mfma_f32_16x16x32_bf16(kaF, bF, akk[n], 0, 0, 0);
        aqk[n] = __builtin_amdgcn_mfma_f32_16x16x32_bf16(qaF, bF, aqk[n], 0, 0, 0);
      }
    }
#pragma unroll
    for (int n = 0; n < 4; ++n)
#pragma unroll
      for (int r = 0; r < 4; ++r) {
        int i = w * 16 + kb * 4 + r;
        int j = n * 16 + r15;
        float e = expf(bl[i] - bl[j]);
        Af[i * 64 + j] = (j < i) ? betal[i] * e * akk[n][r] : 0.f;
        u16 pv = (j <= i) ? f2bf(e * aqk[n][r]) : (u16)0;
        Pg[(size_t)ch * 4096 + i * 64 + j] = pv;
      }
  }
  float b63 = bl[63];
  for (int m = 0; m < 32; ++m) {
    int idx = tid * 32 + m;
    int d = idx >> 6, j = idx & 63;
    float v = bf2f(Kl[j * 128 + d]) * expf(b63 - bl[j]);
    KtTg[(size_t)ch * 8192 + idx] = f2bf(v);
  }
  __syncthreads();
#pragma unroll
  for (int m = 0; m < 16; ++m) Tf[tid * 16 + m] = 0.f;
  __syncthreads();
  if (tid < 64) Tf[tid * 65] = 1.f;
  __syncthreads();
  {
    int ccol = w * 16 + r15;
    int p = kb;
    for (int i = 1; i < 64; ++i) {
      float part = 0.f;
      for (int j = p; j < i; j += 4) part += Af[i * 64 + j] * Tf[j * 64 + ccol];
      part += __shfl_xor(part, 16, 64);
      part += __shfl_xor(part, 32, 64);
      if (p == 0) Tf[i * 64 + ccol] = ((ccol == i) ? 1.f : 0.f) - part;
    }
  }
  __syncthreads();
#pragma unroll
  for (int m = 0; m < 16; ++m) {
    int idx = tid * 16 + m;
    Tg[(size_t)ch * 4096 + idx] = f2bf(Tf[idx]);
  }
}

__global__ __launch_bounds__(512) void chunk_scan_kernel(
    const u16* __restrict__ qkvc, const float* __restrict__ bdpack,
    const u16* __restrict__ Tg, const u16* __restrict__ Pg,
    const u16* __restrict__ KtTg, const float* __restrict__ Bvec,
    u16* __restrict__ obf) {
  __shared__ __align__(16) u16 Kl[64 * 128];
  __shared__ __align__(16) u16 Ql[64 * 128];
  __shared__ __align__(16) u16 KtTl[128 * 64];
  __shared__ __align__(16) u16 Tl[64 * 64];
  __shared__ __align__(16) u16 Pl[64 * 64];
  __shared__ __align__(16) u16 Vl[64 * 32];
  __shared__ __align__(16) u16 St[32 * 128];
  __shared__ __align__(16) u16 rhsT[32 * 64];
  __shared__ __align__(16) u16 dT[32 * 64];
  __shared__ float betal[64], Gl[64];

  int tid = threadIdx.x;
  int w = tid >> 6, l = tid & 63;
  int r15 = l & 15, kb = l >> 4;
  int dvc = blockIdx.x, bh = blockIdx.y;
  int b = bh >> 5, h = bh & 31, hk = h >> 1;
  int a = w >> 1, bcol = w & 1;

  for (int m = tid; m < 32 * 128; m += 512) St[m] = 0;
  f32x4 sAcc0 = {}, sAcc1 = {};
  __syncthreads();

  for (int c = 0; c < 16; ++c) {
    size_t tok0 = (size_t)b * 1024 + c * 64;
    int ch = bh * 16 + c;
#pragma unroll
    for (int rep = 0; rep < 2; ++rep) {
      int gid = w * 128 + rep * 64 + l;
      int row = gid >> 4, seg = gid & 15;
      const u16* srcq = qkvc + (tok0 + row) * CONVC + hk * 128 + seg * 8;
      async16(srcq, Ql + gid * 8);
      async16(srcq + KEYDIM, Kl + gid * 8);
      async16(KtTg + (size_t)ch * 8192 + gid * 8, KtTl + gid * 8);
    }
    {
      int gid = w * 64 + l;
      async16(Tg + (size_t)ch * 4096 + gid * 8, Tl + gid * 8);
      async16(Pg + (size_t)ch * 4096 + gid * 8, Pl + gid * 8);
    }
    if (w < 4) {
      int gid = w * 64 + l;
      int row = gid >> 2, seg = gid & 3;
      async16(qkvc + (tok0 + row) * CONVC + 2 * KEYDIM + h * 128 + dvc * 32 + seg * 8,
              Vl + gid * 8);
    }
    if (tid < 64) {
      betal[tid] = bdpack[((size_t)bh * 1024 + c * 64 + tid) * 2];
      Gl[tid] = Bvec[(size_t)ch * 64 + tid];
    }
    __syncthreads();

    f32x4 aKS = {}, aQS = {};
#pragma unroll
    for (int ks = 0; ks < 4; ++ks) {
      bf16x8 bF = *(const bf16x8*)(St + (bcol * 16 + r15) * 128 + ks * 32 + kb * 8);
      bf16x8 kF = *(const bf16x8*)(Kl + (a * 16 + r15) * 128 + ks * 32 + kb * 8);
      bf16x8 qF = *(const bf16x8*)(Ql + (a * 16 + r15) * 128 + ks * 32 + kb * 8);
      aKS = __builtin_amdgcn_mfma_f32_16x16x32_bf16(kF, bF, aKS, 0, 0, 0);
      aQS = __builtin_amdgcn_mfma_f32_16x16x32_bf16(qF, bF, aQS, 0, 0, 0);
    }
    {
      int i0 = a * 16 + kb * 4;
      int dv = bcol * 16 + r15;
      u16x4 st;
#pragma unroll
      for (int r = 0; r < 4; ++r) {
        int i = i0 + r;
        float v = bf2f(Vl[i * 32 + dv]);
        st[r] = f2bf(betal[i] * (v - Gl[i] * aKS[r]));
      }
      *(u16x4*)(rhsT + dv * 64 + i0) = st;
    }
    __syncthreads();
    f32x4 aD = {};
#pragma unroll
    for (int ks = 0; ks < 2; ++ks) {
      bf16x8 aF = *(const bf16x8*)(Tl + (a * 16 + r15) * 64 + ks * 32 + kb * 8);
      bf16x8 bF = *(const bf16x8*)(rhsT + (bcol * 16 + r15) * 64 + ks * 32 + kb * 8);
      aD = __builtin_amdgcn_mfma_f32_16x16x32_bf16(aF, bF, aD, 0, 0, 0);
    }
    {
      int i0 = a * 16 + kb * 4;
      int dv = bcol * 16 + r15;
      u16x4 st;
#pragma unroll
      for (int r = 0; r < 4; ++r) st[r] = f2bf(aD[r]);
      *(u16x4*)(dT + dv * 64 + i0) = st;
    }
    __syncthreads();
    f32x4 aO = {};
#pragma unroll
    for (int ks = 0; ks < 2; ++ks) {
      bf16x8 aF = *(const bf16x8*)(Pl + (a * 16 + r15) * 64 + ks * 32 + kb * 8);
      bf16x8 bF = *(const bf16x8*)(dT + (bcol * 16 + r15) * 64 + ks * 32 + kb * 8);
      aO = __builtin_amdgcn_mfma_f32_16x16x32_bf16(aF, bF, aO, 0, 0, 0);
    }
    {
      int i0 = a * 16 + kb * 4;
      int dv = bcol * 16 + r15;
#pragma unroll
      for (int r = 0; r < 4; ++r) {
        int i = i0 + r;
        float o = aO[r] + Gl[i] * aQS[r];
        obf[(tok0 + i) * VALDIM + h * 128 + dvc * 32 + dv] = f2bf(o);
      }
    }
    float gL = Gl[63];
#pragma unroll
    for (int r = 0; r < 4; ++r) { sAcc0[r] *= gL; sAcc1[r] *= gL; }
#pragma unroll
    for (int ks = 0; ks < 2; ++ks) {
      bf16x8 aF = *(const bf16x8*)(KtTl + (w * 16 + r15) * 64 + ks * 32 + kb * 8);
      bf16x8 b0 = *(const bf16x8*)(dT + r15 * 64 + ks * 32 + kb * 8);
      bf16x8 b1 = *(const bf16x8*)(dT + (16 + r15) * 64 + ks * 32 + kb * 8);
      sAcc0 = __builtin_amdgcn_mfma_f32_16x16x32_bf16(aF, b0, sAcc0, 0, 0, 0);
      sAcc1 = __builtin_amdgcn_mfma_f32_16x16x32_bf16(aF, b1, sAcc1, 0, 0, 0);
    }
#pragma unroll
    for (int r = 0; r < 4; ++r) {
      int dk = w * 16 + kb * 4 + r;
      St[r15 * 128 + dk] = f2bf(sAcc0[r]);
      St[(16 + r15) * 128 + dk] = f2bf(sAcc1[r]);
    }
    __syncthreads();
  }
}

// -------- gate (silu(z)) + per-head RMSNorm, in-place over z ----------------
__global__ __launch_bounds__(256) void gatenorm_kernel(
    const u16* __restrict__ obf, u16* __restrict__ zb,
    const float* __restrict__ norm_w) {
  int wid = blockIdx.x * 4 + (threadIdx.x >> 6);
  int l = threadIdx.x & 63;
  int tok = wid >> 5, h = wid & 31;
  const u16* op = obf + (size_t)tok * VALDIM + h * 128 + l * 2;
  u16* zp = zb + (size_t)tok * VALDIM + h * 128 + l * 2;
  float o0 = bf2f(op[0]), o1 = bf2f(op[1]);
  float z0 = bf2f(zp[0]), z1 = bf2f(zp[1]);
  float g0 = o0 * siluf(z0);
  float g1 = o1 * siluf(z1);
  float ss = g0 * g0 + g1 * g1;
#pragma unroll
  for (int m = 1; m < 64; m <<= 1) ss += __shfl_xor(ss, m, 64);
  float sc = rsqrtf(ss * (1.f / 128.f) + 1e-6f);
  int e = l * 2;
  *(u32*)zp = pack2(g0 * sc * norm_w[e], g1 * sc * norm_w[e + 1]);
}

// -------- diagnostic --------------------------------------------------------
__global__ void diag_kernel(float* out, float val) { out[0] = val; }

extern "C" void kernel_launch(void* const* d_in, const int* in_sizes, int n_in,
                              void* d_out, int out_size, void* d_ws,
                              size_t ws_size, hipStream_t stream) {
  const float* hidden = (const float*)d_in[1];
  const float* residual = (const float*)d_in[2];
  const float* ln_in_w = (const float*)d_in[3];
  const float* ln_post_w = (const float*)d_in[4];
  const float* Wqkvz = (const float*)d_in[5];
  const float* Wba = (const float*)d_in[6];
  const float* conv_w = (const float*)d_in[7];
  const float* A_log = (const float*)d_in[8];
  const float* dt_bias = (const float*)d_in[9];
  const float* norm_w = (const float*)d_in[10];
  const float* Wout = (const float*)d_in[11];
  const float* Wgate = (const float*)d_in[12];
  const float* Wup = (const float*)d_in[13];
  const float* Wdown = (const float*)d_in[14];

  char* ws = (char*)d_ws;
  size_t off = 0;
  auto alloc = [&](size_t n) {
    char* p = ws + off;
    off = (off + n + 255) & ~(size_t)255;
    return p;
  };
  u16* wslot = (u16*)alloc((size_t)INTER * DMODEL * 2);
  u16* hb = (u16*)alloc((size_t)BT * DMODEL * 2);
  u16* qkvb = (u16*)alloc((size_t)BT * CONVC * 2);
  u16* zb = (u16*)alloc((size_t)BT * VALDIM * 2);
  u16* qkvc = (u16*)alloc((size_t)BT * CONVC * 2);
  float* ba = (float*)alloc((size_t)BT * 64 * 4);
  float* bdpack = (float*)alloc((size_t)64 * 1024 * 2 * 4);
  u16* obf = (u16*)alloc((size_t)BT * VALDIM * 2);
  if (off > ws_size) {
    diag_kernel<<<1, 1, 0, stream>>>((float*)d_out, (float)(ws_size >> 20));
    return;
  }

  float* res1 = (float*)d_out;
  float* attn = (float*)d_out + (size_t)BT * DMODEL;
  float* res2 = attn;
  u16* h2b = hb;
  u16* gbuf = qkvc;
  u16* mbuf = qkvb;
  float* outp = (float*)d_out;

  u16* Tg = qkvb;
  u16* Pg = qkvb + (size_t)1024 * 4096;
  u16* KtTg = qkvb + (size_t)2 * 1024 * 4096;
  float* Bvec = ba;

  float* pWout = (float*)qkvb;  // 2 x 2048x2048 f32 (qkvb dead)
  float* pDown = (float*)zb;    // 4 x 2048x2048 f32 (zb..obf dead)

  dim3 blk(256);
  dim3 blk512(512);

  // 1. res1 = hidden+residual; hb = rmsnorm(res1)
  resnorm_kernel<<<BT, blk, 0, stream>>>(hidden, residual, ln_in_w, res1, hb);

  // 2. qkv-slice GEMM (256-tile deep pipeline)
  convert_transpose<<<dim3(CONVC / 32, DMODEL / 32), blk, 0, stream>>>(
      Wqkvz, QKVZ_N, wslot, DMODEL, CONVC);
  gemm256_kernel<1><<<dim3(CONVC / 256, BT / 256), blk512, 0, stream>>>(
      hb, wslot, qkvb, nullptr, BT, CONVC, DMODEL, DMODEL);

  // 3. z-slice GEMM (128-tile)
  convert_transpose<<<dim3(VALDIM / 32, DMODEL / 32), blk, 0, stream>>>(
      Wqkvz + CONVC, QKVZ_N, wslot, DMODEL, VALDIM);
  gemm_kernel<1><<<dim3(VALDIM / 128, BT / 128), blk, 0, stream>>>(
      hb, wslot, zb, nullptr, BT, VALDIM, DMODEL, DMODEL);

  // 4. ba = hb @ Wba
  ba_gemm_kernel<<<BT, blk, 0, stream>>>(hb, Wba, ba);

  // 5-7. conv+silu, l2norm(q,k), beta/decay
  conv_silu_kernel<<<BT * 2048 / 256, blk, 0, stream>>>(qkvb, conv_w, qkvc);
  l2norm_kernel<<<BT * 32 / 4, blk, 0, stream>>>(qkvc);
  betadecay_kernel<<<BT * HV / 256, blk, 0, stream>>>(ba, A_log, dt_bias,
                                                      bdpack);

  // 8. chunked gated delta rule scan
  prep_kernel<<<dim3(16, 64), blk, 0, stream>>>(qkvc, bdpack, Tg, Pg, KtTg,
                                                Bvec);
  chunk_scan_kernel<<<dim3(4, 64), dim3(512), 0, stream>>>(
      qkvc, bdpack, Tg, Pg, KtTg, Bvec, obf);

  // 9. gate + per-head RMSNorm (in place over zb)
  gatenorm_kernel<<<BT * HV / 4, blk, 0, stream>>>(obf, zb, norm_w);

  // 10. attn = og @ Wout (128-tile, split-K=2, partials in dead qkvb)
  convert_transpose<<<dim3(DMODEL / 32, VALDIM / 32), blk, 0, stream>>>(
      Wout, DMODEL, wslot, VALDIM, DMODEL);
  gemm_kernel<0><<<dim3(DMODEL / 128, BT / 128, 2), blk, 0, stream>>>(
      zb, wslot, pWout, nullptr, BT, DMODEL, VALDIM, VALDIM / 2);
  reduce_kernel<<<BT * DMODEL / 1024, blk, 0, stream>>>(pWout, attn,
                                                        BT * DMODEL, 2);

  // 11. res2 = attn + res1; h2b = rmsnorm(res2)
  resnorm_kernel<<<BT, blk, 0, stream>>>(attn, res1, ln_post_w, res2, h2b);

  // 12. gate GEMM (256-tile)
  convert_transpose<<<dim3(INTER / 32, DMODEL / 32), blk, 0, stream>>>(
      Wgate, INTER, wslot, DMODEL, INTER);
  gemm256_kernel<1><<<dim3(INTER / 256, BT / 256), blk512, 0, stream>>>(
      h2b, wslot, gbuf, nullptr, BT, INTER, DMODEL, DMODEL);

  // 13. up GEMM fused with m = silu(g)*u (256-tile)
  convert_transpose<<<dim3(INTER / 32, DMODEL / 32), blk, 0, stream>>>(
      Wup, INTER, wslot, DMODEL, INTER);
  gemm256_kernel<2><<<dim3(INTER / 256, BT / 256), blk512, 0, stream>>>(
      h2b, wslot, mbuf, gbuf, BT, INTER, DMODEL, DMODEL);

  // 14. out = m @ Wdown (256-tile, split-K=4, partials in dead zb..obf)
  convert_transpose<<<dim3(DMODEL / 32, INTER / 32), blk, 0, stream>>>(
      Wdown, DMODEL, wslot, INTER, DMODEL);
  gemm256_kernel<0><<<dim3(DMODEL / 256, BT / 256, 4), blk512, 0, stream>>>(
      mbuf, wslot, pDown, nullptr, BT, DMODEL, INTER, INTER / 4);
  reduce_kernel<<<BT * DMODEL / 1024, blk, 0, stream>>>(pDown, outp,
                                                        BT * DMODEL, 4);
}

// Round 11
// 824.820 us; speedup vs baseline: 1.2488x; 1.0611x over previous
//
#include <hip/hip_runtime.h>
#include <hip/hip_bf16.h>

typedef unsigned short u16;
typedef unsigned int u32;
typedef float f32x4 __attribute__((ext_vector_type(4)));
typedef short bf16x8 __attribute__((ext_vector_type(8)));
typedef unsigned short u16x4 __attribute__((ext_vector_type(4)));
typedef unsigned int u32x2 __attribute__((ext_vector_type(2)));
typedef unsigned int u32x4 __attribute__((ext_vector_type(4)));

#define BT 2048            // B*T
#define DMODEL 2048
#define HV 32
#define DK 128
#define KEYDIM 2048
#define VALDIM 4096
#define QKVZ_N 12288
#define CONVC 8192         // q,k,v channels
#define INTER 8192

__device__ __forceinline__ float bf2f(u16 v) {
  u32 u = ((u32)v) << 16;
  return __builtin_bit_cast(float, u);
}
__device__ __forceinline__ u16 f2bf(float f) {
  u32 u = __builtin_bit_cast(u32, f);
  u32 r = (u + 0x7fffu + ((u >> 16) & 1u)) >> 16;
  return (u16)r;
}
__device__ __forceinline__ u32 pack2(float a, float b) {
  return (u32)f2bf(a) | ((u32)f2bf(b) << 16);
}
__device__ __forceinline__ float siluf(float x) {
  return x / (1.f + expf(-x));
}

// -------- weight convert+transpose: W[K,N] f32 (row stride ldw) -> Wt[N,K] bf16
__global__ __launch_bounds__(256) void convert_transpose(
    const float* __restrict__ W, int ldw, u16* __restrict__ Wt, int K, int N) {
  __shared__ float tile[32][33];
  int n0 = blockIdx.x * 32, k0 = blockIdx.y * 32;
  int tx = threadIdx.x & 31, ty = threadIdx.x >> 5;  // ty 0..7
#pragma unroll
  for (int i = 0; i < 4; ++i) {
    int kk = ty + i * 8;
    tile[kk][tx] = W[(size_t)(k0 + kk) * ldw + n0 + tx];
  }
  __syncthreads();
#pragma unroll
  for (int i = 0; i < 4; ++i) {
    int nn = ty + i * 8;
    Wt[(size_t)(n0 + nn) * K + k0 + tx] = f2bf(tile[tx][nn]);
  }
}

// -------- fused residual add + gemma RMSNorm (a+b -> resout f32, norm -> bf16)
__global__ __launch_bounds__(256) void resnorm_kernel(
    const float* __restrict__ a, const float* __restrict__ b,
    const float* __restrict__ w, float* __restrict__ resout,
    u16* __restrict__ hb) {
  int tok = blockIdx.x, t = threadIdx.x;
  const float* ap = a + (size_t)tok * DMODEL + t * 8;
  const float* bp = b + (size_t)tok * DMODEL + t * 8;
  f32x4 x0 = *(const f32x4*)ap + *(const f32x4*)bp;
  f32x4 x1 = *(const f32x4*)(ap + 4) + *(const f32x4*)(bp + 4);
  *(f32x4*)(resout + (size_t)tok * DMODEL + t * 8) = x0;
  *(f32x4*)(resout + (size_t)tok * DMODEL + t * 8 + 4) = x1;
  float ss = 0.f;
#pragma unroll
  for (int j = 0; j < 4; ++j) ss += x0[j] * x0[j] + x1[j] * x1[j];
#pragma unroll
  for (int m = 1; m < 64; m <<= 1) ss += __shfl_xor(ss, m, 64);
  __shared__ float red[4];
  if ((t & 63) == 0) red[t >> 6] = ss;
  __syncthreads();
  ss = red[0] + red[1] + red[2] + red[3];
  float sc = rsqrtf(ss * (1.f / (float)DMODEL) + 1e-6f);
  const float* wp = w + t * 8;
  float y[8];
#pragma unroll
  for (int j = 0; j < 4; ++j) {
    y[j] = x0[j] * sc * (1.f + wp[j]);
    y[4 + j] = x1[j] * sc * (1.f + wp[4 + j]);
  }
  u32x4 st;
  st[0] = pack2(y[0], y[1]);
  st[1] = pack2(y[2], y[3]);
  st[2] = pack2(y[4], y[5]);
  st[3] = pack2(y[6], y[7]);
  *(u32x4*)(hb + (size_t)tok * DMODEL + t * 8) = st;
}

__device__ __forceinline__ void async16(const void* g, void* l) {
  __builtin_amdgcn_global_load_lds(
      (const __attribute__((address_space(1))) u32*)g,
      (__attribute__((address_space(3))) u32*)l, 16, 0, 0);
}

// -------- 128-tile MFMA GEMM (proven round-8): ring-4, counted vmcnt --------
template <int OUT>
__global__ __launch_bounds__(256) void gemm_kernel(
    const u16* __restrict__ A, const u16* __restrict__ Bt,
    void* __restrict__ Cv, const u16* __restrict__ Aux, int M, int N,
    int Kfull, int Ks) {
  __shared__ __align__(16) u16 Al[4][128 * 32];
  __shared__ __align__(16) u16 Bl[4][128 * 32];
  int tid = threadIdx.x;
  int w = tid >> 6, l = tid & 63;
  int wr = w >> 1, wc = w & 1;
  int r15 = l & 15, kb = l >> 4;

  int nbx = gridDim.x, nby = gridDim.y;
  int bid = blockIdx.y * nbx + blockIdx.x;
  int nwg = nbx * nby;
  int cpx = nwg >> 3;
  int wg = (bid & 7) * cpx + (bid >> 3);
  const int GRP = 4;
  int span = GRP * nby;
  int grpId = wg / span;
  int rem = wg - grpId * span;
  int n0 = (grpId * GRP + (rem % GRP)) * 128;
  int m0 = (rem / GRP) * 128;
  int kbase = blockIdx.z * Ks;

  f32x4 acc[4][4] = {};

  auto stage = [&](int buf, int kt) {
#pragma unroll
    for (int c = 0; c < 2; ++c) {
      int gid = w * 128 + c * 64 + l;
      int row = gid >> 2;
      int g = (gid & 3) ^ ((row >> 1) & 3);
      async16(A + (size_t)(m0 + row) * Kfull + kt + g * 8, Al[buf] + gid * 8);
      async16(Bt + (size_t)(n0 + row) * Kfull + kt + g * 8, Bl[buf] + gid * 8);
    }
  };

  int nst = Ks >> 5;
#pragma unroll
  for (int p = 0; p < 3; ++p)
    if (p < nst) stage(p & 3, kbase + p * 32);

  for (int i = 0; i < nst; ++i) {
    int issued = (i + 3 < nst) ? (i + 3) : nst;
    int infl = issued - i - 1;
    if (infl >= 2)
      asm volatile("s_waitcnt vmcnt(8)" ::: "memory");
    else if (infl == 1)
      asm volatile("s_waitcnt vmcnt(4)" ::: "memory");
    else
      asm volatile("s_waitcnt vmcnt(0)" ::: "memory");
    __builtin_amdgcn_s_barrier();
    __builtin_amdgcn_sched_barrier(0);
    if (i + 3 < nst) stage((i + 3) & 3, kbase + (i + 3) * 32);
    const u16* Ac = Al[i & 3];
    const u16* Bc = Bl[i & 3];
    bf16x8 aF[4], bF[4];
#pragma unroll
    for (int m = 0; m < 4; ++m) {
      int row = wr * 64 + m * 16 + r15;
      aF[m] = *(const bf16x8*)(Ac + row * 32 + (kb ^ ((row >> 1) & 3)) * 8);
    }
#pragma unroll
    for (int n = 0; n < 4; ++n) {
      int row = wc * 64 + n * 16 + r15;
      bF[n] = *(const bf16x8*)(Bc + row * 32 + (kb ^ ((row >> 1) & 3)) * 8);
    }
#pragma unroll
    for (int m = 0; m < 4; ++m)
#pragma unroll
      for (int n = 0; n < 4; ++n)
        acc[m][n] = __builtin_amdgcn_mfma_f32_16x16x32_bf16(aF[m], bF[n],
                                                            acc[m][n], 0, 0, 0);
  }

  float* Cf = (float*)Cv + (size_t)blockIdx.z * M * N;
#pragma unroll
  for (int m = 0; m < 4; ++m)
#pragma unroll
    for (int n = 0; n < 4; ++n) {
      size_t base = (size_t)(m0 + wr * 64 + m * 16 + kb * 4) * N +
                    (n0 + wc * 64 + n * 16 + r15);
#pragma unroll
      for (int r = 0; r < 4; ++r) {
        size_t idx = base + (size_t)r * N;
        if (OUT == 0)
          Cf[idx] = acc[m][n][r];
        else if (OUT == 1)
          ((u16*)Cv)[idx] = f2bf(acc[m][n][r]);
        else
          ((u16*)Cv)[idx] = f2bf(siluf(bf2f(Aux[idx])) * acc[m][n][r]);
      }
    }
}

// -------- 256-tile 4-phase deep-pipeline GEMM (m201-style, BK=64, 512 thr) --
// LDS: 8 chunks [256][32]u16 (2buf x {A,B} x 2 k-halves) = 128KB; lane pattern
// identical to the proven 0-conflict 128-tile kernel (key=(row>>1)&3).
// Per K-tile 4 phases (ks,q): {ds_read 4-8; stage 1 unit of t+1; barrier;
// lgkm(0)+sched_barrier; setprio1; 16 MFMA; setprio0; [vmcnt(4) @ph2,ph4];
// barrier}. Invariant: at each vmcnt(4) the oldest 4 loads = the k-half
// needed one phase later; never drains to 0 except the final tile.
#define GPHASE(ACHUNK, BCHUNK, Q, READ_B, ST_OP, ST_KH, TAILVM)              \
  {                                                                          \
    if (READ_B) {                                                            \
      _Pragma("unroll") for (int n = 0; n < 4; ++n) {                        \
        int row = wn * 64 + n * 16 + r15;                                    \
        bF[n] = *(const bf16x8*)((BCHUNK) + row * 32 +                       \
                                 (kb ^ ((row >> 1) & 3)) * 8);               \
      }                                                                      \
    }                                                                        \
    _Pragma("unroll") for (int mm = 0; mm < 4; ++mm) {                       \
      int row = wm * 128 + (Q)*64 + mm * 16 + r15;                           \
      aF[mm] = *(const bf16x8*)((ACHUNK) + row * 32 +                        \
                                (kb ^ ((row >> 1) & 3)) * 8);                \
    }                                                                        \
    if (hn) stage(buf ^ 1, ST_OP, ST_KH, nc);                                \
    __builtin_amdgcn_s_barrier();                                            \
    asm volatile("s_waitcnt lgkmcnt(0)" ::: "memory");                       \
    __builtin_amdgcn_sched_barrier(0);                                       \
    __builtin_amdgcn_s_setprio(1);                                           \
    _Pragma("unroll") for (int mm = 0; mm < 4; ++mm)                         \
        _Pragma("unroll") for (int n = 0; n < 4; ++n)                        \
            acc[(Q)*4 + mm][n] = __builtin_amdgcn_mfma_f32_16x16x32_bf16(    \
                aF[mm], bF[n], acc[(Q)*4 + mm][n], 0, 0, 0);                 \
    __builtin_amdgcn_s_setprio(0);                                           \
    if (TAILVM) {                                                            \
      if (hn)                                                                \
        asm volatile("s_waitcnt vmcnt(4)" ::: "memory");                     \
      else                                                                   \
        asm volatile("s_waitcnt vmcnt(0)" ::: "memory");                     \
    }                                                                        \
    __builtin_amdgcn_s_barrier();                                            \
  }

template <int OUT>
__global__ __launch_bounds__(512, 2) void gemm256_kernel(
    const u16* __restrict__ A, const u16* __restrict__ Bt,
    void* __restrict__ Cv, const u16* __restrict__ Aux, int M, int N,
    int Kfull, int Ks) {
  __shared__ __align__(16) u16 S[65536];  // 128 KB: [buf][op][kh][256][32]
  int tid = threadIdx.x;
  int l = tid & 63, w = tid >> 6;
  int wm = w >> 2, wn = w & 3;  // 2M x 4N waves; wave tile 128(M) x 64(N)
  int r15 = l & 15, kb = l >> 4;

  int nbx = gridDim.x, nby = gridDim.y;  // N/256, M/256
  int bid = blockIdx.y * nbx + blockIdx.x;
  int nwg = nbx * nby;
  int cpx = nwg >> 3;
  int wg = (bid & 7) * cpx + (bid >> 3);
  const int GRP = 4;
  int span = GRP * nby;
  int grpId = wg / span;
  int rem = wg - grpId * span;
  int n0 = (grpId * GRP + (rem % GRP)) * 256;
  int m0 = (rem / GRP) * 256;
  int kbase = blockIdx.z * Ks;

  f32x4 acc[8][4] = {};

  // stage one 16KB unit: (op, kh) of K-tile at col base ktcol into buf
  auto stage = [&](int buf, int op, int kh, int ktcol) {
#pragma unroll
    for (int c = 0; c < 2; ++c) {
      int gid = c * 512 + tid;  // 1024 granules = 256 rows x 4
      int row = gid >> 2, gg = gid & 3;
      int gl = gg ^ ((row >> 1) & 3);
      const u16* src = (op == 0 ? A + (size_t)(m0 + row) * Kfull
                                : Bt + (size_t)(n0 + row) * Kfull) +
                       ktcol + kh * 32 + gl * 8;
      async16(src, S + ((buf * 2 + op) * 2 + kh) * 8192 + gid * 8);
    }
  };

  int nt = Ks >> 6;  // K-tiles of 64 (all call sites: nt = 32)
  // prologue: tile 0, units in steady-state order Akh0,Bkh0,Akh1,Bkh1
  stage(0, 0, 0, kbase);
  stage(0, 1, 0, kbase);
  stage(0, 0, 1, kbase);
  stage(0, 1, 1, kbase);
  asm volatile("s_waitcnt vmcnt(4)" ::: "memory");  // kh0 pair ready
  __builtin_amdgcn_s_barrier();

  for (int t = 0; t < nt; ++t) {
    int buf = t & 1;
    bool hn = t + 1 < nt;
    int nc = kbase + (t + 1) * 64;
    const u16* Ac0 = S + ((buf * 2 + 0) * 2 + 0) * 8192;
    const u16* Ac1 = S + ((buf * 2 + 0) * 2 + 1) * 8192;
    const u16* Bc0 = S + ((buf * 2 + 1) * 2 + 0) * 8192;
    const u16* Bc1 = S + ((buf * 2 + 1) * 2 + 1) * 8192;
    bf16x8 aF[4], bF[4];
    GPHASE(Ac0, Bc0, 0, true, 0, 0, false)   // ks0 q0; stage A kh0 (t+1)
    GPHASE(Ac0, Bc0, 1, false, 1, 0, true)   // ks0 q1; stage B kh0; vmcnt(4)
    GPHASE(Ac1, Bc1, 0, true, 0, 1, false)   // ks1 q0; stage A kh1 (t+1)
    GPHASE(Ac1, Bc1, 1, false, 1, 1, true)   // ks1 q1; stage B kh1; vmcnt(4)
  }

  float* Cf = (float*)Cv + (size_t)blockIdx.z * M * N;
#pragma unroll
  for (int m = 0; m < 8; ++m)
#pragma unroll
    for (int n = 0; n < 4; ++n) {
      size_t base = (size_t)(m0 + wm * 128 + m * 16 + kb * 4) * N +
                    (n0 + wn * 64 + n * 16 + r15);
#pragma unroll
      for (int r = 0; r < 4; ++r) {
        size_t idx = base + (size_t)r * N;
        if (OUT == 0)
          Cf[idx] = acc[m][n][r];
        else if (OUT == 1)
          ((u16*)Cv)[idx] = f2bf(acc[m][n][r]);
        else
          ((u16*)Cv)[idx] = f2bf(siluf(bf2f(Aux[idx])) * acc[m][n][r]);
      }
    }
}

// -------- split-K reduce: out[i] = sum_s parts[s*n + i] ---------------------
__global__ __launch_bounds__(256) void reduce_kernel(
    const float* __restrict__ p, float* __restrict__ o, int n, int S) {
  int i = (blockIdx.x * 256 + threadIdx.x) * 4;
  f32x4 s = *(const f32x4*)(p + i);
  for (int j = 1; j < S; ++j) s += *(const f32x4*)(p + (size_t)j * n + i);
  *(f32x4*)(o + i) = s;
}

// -------- ba = hb(bf16) @ Wba(f32 [2048,64]) --------------------------------
__global__ __launch_bounds__(256) void ba_gemm_kernel(
    const u16* __restrict__ hb, const float* __restrict__ Wba,
    float* __restrict__ ba) {
  int m = blockIdx.x;
  int t = threadIdx.x;
  int n = t & 63, kq = t >> 6;
  const u16* a = hb + (size_t)m * DMODEL + kq * 512;
  const float* wp = Wba + (size_t)kq * 512 * 64 + n;
  float sum = 0.f;
  for (int i = 0; i < 512; ++i)
    sum += bf2f(a[i]) * wp[(size_t)i * 64];
  __shared__ float red[256];
  red[t] = sum;
  __syncthreads();
  if (t < 64)
    ba[(size_t)m * 64 + t] = red[t] + red[t + 64] + red[t + 128] + red[t + 192];
}

// -------- causal depthwise conv (K=4) + SiLU, bf16 in/out -------------------
__global__ __launch_bounds__(256) void conv_silu_kernel(
    const u16* __restrict__ qkvb, const float* __restrict__ conv_w,
    u16* __restrict__ qkv) {
  int gid = blockIdx.x * 256 + threadIdx.x;
  int c4 = (gid & 2047) * 4;
  int bt = gid >> 11;
  int b = bt >> 10, tt = bt & 1023;
  f32x4 wv[4];
#pragma unroll
  for (int j = 0; j < 4; ++j) wv[j] = *(const f32x4*)(conv_w + (c4 + j) * 4);
  float acc[4] = {0.f, 0.f, 0.f, 0.f};
#pragma unroll
  for (int i = 0; i < 4; ++i) {
    int ts = tt - 3 + i;
    if (ts >= 0) {
      u16x4 x = *(const u16x4*)(qkvb + (size_t)(b * 1024 + ts) * CONVC + c4);
#pragma unroll
      for (int j = 0; j < 4; ++j) acc[j] += bf2f(x[j]) * wv[j][i];
    }
  }
  u32x2 st;
  st[0] = pack2(siluf(acc[0]), siluf(acc[1]));
  st[1] = pack2(siluf(acc[2]), siluf(acc[3]));
  *(u32x2*)(qkv + (size_t)bt * CONVC + c4) = st;
}

// -------- l2 norm of q,k heads in place (bf16), q also * DK^-0.5 ------------
__global__ __launch_bounds__(256) void l2norm_kernel(u16* __restrict__ qkv) {
  int wid = blockIdx.x * 4 + (threadIdx.x >> 6);
  int l = threadIdx.x & 63;
  int tok = wid >> 5, slot = wid & 31;
  u16* p = qkv + (size_t)tok * CONVC + slot * 128 + l * 2;
  float x0 = bf2f(p[0]), x1 = bf2f(p[1]);
  float ss = x0 * x0 + x1 * x1;
#pragma unroll
  for (int m = 1; m < 64; m <<= 1) ss += __shfl_xor(ss, m, 64);
  float sc = rsqrtf(ss + 1e-6f);
  if (slot < 16) sc *= 0.08838834764831845f;  // DK^-0.5
  *(u32*)p = pack2(x0 * sc, x1 * sc);
}

// -------- bd[(b*32+h)][t][2] = {sigmoid(bb), exp(-exp(A_log)*softplus)} -----
__global__ __launch_bounds__(256) void betadecay_kernel(
    const float* __restrict__ ba, const float* __restrict__ A_log,
    const float* __restrict__ dt_bias, float* __restrict__ bd) {
  int idx = blockIdx.x * 256 + threadIdx.x;
  int h = idx & 31;
  int tok = idx >> 5;
  int b = tok >> 10, tt = tok & 1023;
  float bb = ba[(size_t)tok * 64 + h];
  float aa = ba[(size_t)tok * 64 + 32 + h];
  float bet = 1.f / (1.f + expf(-bb));
  float x = aa + dt_bias[h];
  float sp = (x > 20.f) ? x : log1pf(expf(x));
  float dec = expf(-expf(A_log[h]) * sp);
  size_t o = (((size_t)(b * 32 + h)) * 1024 + tt) * 2;
  bd[o] = bet;
  bd[o + 1] = dec;
}

// ======================= chunked delta-rule scan ============================
__global__ __launch_bounds__(256) void prep_kernel(
    const u16* __restrict__ qkvc, const float* __restrict__ bdpack,
    u16* __restrict__ Tg, u16* __restrict__ Pg, u16* __restrict__ KtTg,
    float* __restrict__ Bvec) {
  __shared__ __align__(16) u16 Kl[64 * 128];
  __shared__ __align__(16) u16 Ql[64 * 128];
  __shared__ __align__(16) float Af[64 * 64];
  __shared__ __align__(16) float Tf[64 * 64];
  __shared__ float lgl[64], bl[64], betal[64];
  int tid = threadIdx.x;
  int w = tid >> 6, l = tid & 63;
  int r15 = l & 15, kb = l >> 4;
  int c = blockIdx.x, bh = blockIdx.y;
  int b = bh >> 5, h = bh & 31, hk = h >> 1;
  size_t tok0 = (size_t)b * 1024 + c * 64;
  int ch = bh * 16 + c;

#pragma unroll
  for (int rep = 0; rep < 4; ++rep) {
    int gid = w * 256 + rep * 64 + l;
    int row = gid >> 4, seg = gid & 15;
    const u16* srcq = qkvc + (tok0 + row) * CONVC + hk * 128 + seg * 8;
    async16(srcq, Ql + gid * 8);
    async16(srcq + KEYDIM, Kl + gid * 8);
  }
  if (tid < 64) {
    size_t o = ((size_t)bh * 1024 + c * 64 + tid) * 2;
    betal[tid] = bdpack[o];
    lgl[tid] = logf(fmaxf(bdpack[o + 1], 1e-30f));
  }
  __syncthreads();
  if (tid < 64) {
    float s = 0.f;
    for (int j = 0; j <= tid; ++j) s += lgl[j];
    bl[tid] = s;
    Bvec[(size_t)ch * 64 + tid] = expf(s);
  }
  __syncthreads();

  {
    f32x4 akk[4] = {}, aqk[4] = {};
#pragma unroll
    for (int ks = 0; ks < 4; ++ks) {
      bf16x8 kaF = *(const bf16x8*)(Kl + (w * 16 + r15) * 128 + ks * 32 + kb * 8);
      bf16x8 qaF = *(const bf16x8*)(Ql + (w * 16 + r15) * 128 + ks * 32 + kb * 8);
#pragma unroll
      for (int n = 0; n < 4; ++n) {
        bf16x8 bF = *(const bf16x8*)(Kl + (n * 16 + r15) * 128 + ks * 32 + kb * 8);
        akk[n] = __builtin_amdgcn_mfma_f32_16x16x32_bf16(kaF, bF, akk[n], 0, 0, 0);
        aqk[n] = __builtin_amdgcn_mfma_f32_16x16x32_bf16(qaF, bF, aqk[n], 0, 0, 0);
      }
    }
#pragma unroll
    for (int n = 0; n < 4; ++n)
#pragma unroll
      for (int r = 0; r < 4; ++r) {
        int i = w * 16 + kb * 4 + r;
        int j = n * 16 + r15;
        float e = expf(bl[i] - bl[j]);
        Af[i * 64 + j] = (j < i) ? betal[i] * e * akk[n][r] : 0.f;
        u16 pv = (j <= i) ? f2bf(e * aqk[n][r]) : (u16)0;
        Pg[(size_t)ch * 4096 + i * 64 + j] = pv;
      }
  }
  float b63 = bl[63];
  for (int m = 0; m < 32; ++m) {
    int idx = tid * 32 + m;
    int d = idx >> 6, j = idx & 63;
    float v = bf2f(Kl[j * 128 + d]) * expf(b63 - bl[j]);
    KtTg[(size_t)ch * 8192 + idx] = f2bf(v);
  }
  __syncthreads();
#pragma unroll
  for (int m = 0; m < 16; ++m) Tf[tid * 16 + m] = 0.f;
  __syncthreads();
  if (tid < 64) Tf[tid * 65] = 1.f;
  __syncthreads();
  {
    int ccol = w * 16 + r15;
    int p = kb;
    for (int i = 1; i < 64; ++i) {
      float part = 0.f;
      for (int j = p; j < i; j += 4) part += Af[i * 64 + j] * Tf[j * 64 + ccol];
      part += __shfl_xor(part, 16, 64);
      part += __shfl_xor(part, 32, 64);
      if (p == 0) Tf[i * 64 + ccol] = ((ccol == i) ? 1.f : 0.f) - part;
    }
  }
  __syncthreads();
#pragma unroll
  for (int m = 0; m < 16; ++m) {
    int idx = tid * 16 + m;
    Tg[(size_t)ch * 4096 + idx] = f2bf(Tf[idx]);
  }
}

__global__ __launch_bounds__(512) void chunk_scan_kernel(
    const u16* __restrict__ qkvc, const float* __restrict__ bdpack,
    const u16* __restrict__ Tg, const u16* __restrict__ Pg,
    const u16* __restrict__ KtTg, const float* __restrict__ Bvec,
    u16* __restrict__ obf) {
  __shared__ __align__(16) u16 Kl[64 * 128];
  __shared__ __align__(16) u16 Ql[64 * 128];
  __shared__ __align__(16) u16 KtTl[128 * 64];
  __shared__ __align__(16) u16 Tl[64 * 64];
  __shared__ __align__(16) u16 Pl[64 * 64];
  __shared__ __align__(16) u16 Vl[64 * 32];
  __shared__ __align__(16) u16 St[32 * 128];
  __shared__ __align__(16) u16 rhsT[32 * 64];
  __shared__ __align__(16) u16 dT[32 * 64];
  __shared__ float betal[64], Gl[64];

  int tid = threadIdx.x;
  int w = tid >> 6, l = tid & 63;
  int r15 = l & 15, kb = l >> 4;
  int dvc = blockIdx.x, bh = blockIdx.y;
  int b = bh >> 5, h = bh & 31, hk = h >> 1;
  int a = w >> 1, bcol = w & 1;

  for (int m = tid; m < 32 * 128; m += 512) St[m] = 0;
  f32x4 sAcc0 = {}, sAcc1 = {};
  __syncthreads();

  for (int c = 0; c < 16; ++c) {
    size_t tok0 = (size_t)b * 1024 + c * 64;
    int ch = bh * 16 + c;
#pragma unroll
    for (int rep = 0; rep < 2; ++rep) {
      int gid = w * 128 + rep * 64 + l;
      int row = gid >> 4, seg = gid & 15;
      const u16* srcq = qkvc + (tok0 + row) * CONVC + hk * 128 + seg * 8;
      async16(srcq, Ql + gid * 8);
      async16(srcq + KEYDIM, Kl + gid * 8);
      async16(KtTg + (size_t)ch * 8192 + gid * 8, KtTl + gid * 8);
    }
    {
      int gid = w * 64 + l;
      async16(Tg + (size_t)ch * 4096 + gid * 8, Tl + gid * 8);
      async16(Pg + (size_t)ch * 4096 + gid * 8, Pl + gid * 8);
    }
    if (w < 4) {
      int gid = w * 64 + l;
      int row = gid >> 2, seg = gid & 3;
      async16(qkvc + (tok0 + row) * CONVC + 2 * KEYDIM + h * 128 + dvc * 32 + seg * 8,
              Vl + gid * 8);
    }
    if (tid < 64) {
      betal[tid] = bdpack[((size_t)bh * 1024 + c * 64 + tid) * 2];
      Gl[tid] = Bvec[(size_t)ch * 64 + tid];
    }
    __syncthreads();

    f32x4 aKS = {}, aQS = {};
#pragma unroll
    for (int ks = 0; ks < 4; ++ks) {
      bf16x8 bF = *(const bf16x8*)(St + (bcol * 16 + r15) * 128 + ks * 32 + kb * 8);
      bf16x8 kF = *(const bf16x8*)(Kl + (a * 16 + r15) * 128 + ks * 32 + kb * 8);
      bf16x8 qF = *(const bf16x8*)(Ql + (a * 16 + r15) * 128 + ks * 32 + kb * 8);
      aKS = __builtin_amdgcn_mfma_f32_16x16x32_bf16(kF, bF, aKS, 0, 0, 0);
      aQS = __builtin_amdgcn_mfma_f32_16x16x32_bf16(qF, bF, aQS, 0, 0, 0);
    }
    {
      int i0 = a * 16 + kb * 4;
      int dv = bcol * 16 + r15;
      u16x4 st;
#pragma unroll
      for (int r = 0; r < 4; ++r) {
        int i = i0 + r;
        float v = bf2f(Vl[i * 32 + dv]);
        st[r] = f2bf(betal[i] * (v - Gl[i] * aKS[r]));
      }
      *(u16x4*)(rhsT + dv * 64 + i0) = st;
    }
    __syncthreads();
    f32x4 aD = {};
#pragma unroll
    for (int ks = 0; ks < 2; ++ks) {
      bf16x8 aF = *(const bf16x8*)(Tl + (a * 16 + r15) * 64 + ks * 32 + kb * 8);
      bf16x8 bF = *(const bf16x8*)(rhsT + (bcol * 16 + r15) * 64 + ks * 32 + kb * 8);
      aD = __builtin_amdgcn_mfma_f32_16x16x32_bf16(aF, bF, aD, 0, 0, 0);
    }
    {
      int i0 = a * 16 + kb * 4;
      int dv = bcol * 16 + r15;
      u16x4 st;
#pragma unroll
      for (int r = 0; r < 4; ++r) st[r] = f2bf(aD[r]);
      *(u16x4*)(dT + dv * 64 + i0) = st;
    }
    __syncthreads();
    f32x4 aO = {};
#pragma unroll
    for (int ks = 0; ks < 2; ++ks) {
      bf16x8 aF = *(const bf16x8*)(Pl + (a * 16 + r15) * 64 + ks * 32 + kb * 8);
      bf16x8 bF = *(const bf16x8*)(dT + (bcol * 16 + r15) * 64 + ks * 32 + kb * 8);
      aO = __builtin_amdgcn_mfma_f32_16x16x32_bf16(aF, bF, aO, 0, 0, 0);
    }
    {
      int i0 = a * 16 + kb * 4;
      int dv = bcol * 16 + r15;
#pragma unroll
      for (int r = 0; r < 4; ++r) {
        int i = i0 + r;
        float o = aO[r] + Gl[i] * aQS[r];
        obf[(tok0 + i) * VALDIM + h * 128 + dvc * 32 + dv] = f2bf(o);
      }
    }
    float gL = Gl[63];
#pragma unroll
    for (int r = 0; r < 4; ++r) { sAcc0[r] *= gL; sAcc1[r] *= gL; }
#pragma unroll
    for (int ks = 0; ks < 2; ++ks) {
      bf16x8 aF = *(const bf16x8*)(KtTl + (w * 16 + r15) * 64 + ks * 32 + kb * 8);
      bf16x8 b0 = *(const bf16x8*)(dT + r15 * 64 + ks * 32 + kb * 8);
      bf16x8 b1 = *(const bf16x8*)(dT + (16 + r15) * 64 + ks * 32 + kb * 8);
      sAcc0 = __builtin_amdgcn_mfma_f32_16x16x32_bf16(aF, b0, sAcc0, 0, 0, 0);
      sAcc1 = __builtin_amdgcn_mfma_f32_16x16x32_bf16(aF, b1, sAcc1, 0, 0, 0);
    }
#pragma unroll
    for (int r = 0; r < 4; ++r) {
      int dk = w * 16 + kb * 4 + r;
      St[r15 * 128 + dk] = f2bf(sAcc0[r]);
      St[(16 + r15) * 128 + dk] = f2bf(sAcc1[r]);
    }
    __syncthreads();
  }
}

// -------- gate (silu(z)) + per-head RMSNorm, in-place over z ----------------
__global__ __launch_bounds__(256) void gatenorm_kernel(
    const u16* __restrict__ obf, u16* __restrict__ zb,
    const float* __restrict__ norm_w) {
  int wid = blockIdx.x * 4 + (threadIdx.x >> 6);
  int l = threadIdx.x & 63;
  int tok = wid >> 5, h = wid & 31;
  const u16* op = obf + (size_t)tok * VALDIM + h * 128 + l * 2;
  u16* zp = zb + (size_t)tok * VALDIM + h * 128 + l * 2;
  float o0 = bf2f(op[0]), o1 = bf2f(op[1]);
  float z0 = bf2f(zp[0]), z1 = bf2f(zp[1]);
  float g0 = o0 * siluf(z0);
  float g1 = o1 * siluf(z1);
  float ss = g0 * g0 + g1 * g1;
#pragma unroll
  for (int m = 1; m < 64; m <<= 1) ss += __shfl_xor(ss, m, 64);
  float sc = rsqrtf(ss * (1.f / 128.f) + 1e-6f);
  int e = l * 2;
  *(u32*)zp = pack2(g0 * sc * norm_w[e], g1 * sc * norm_w[e + 1]);
}

// -------- diagnostic --------------------------------------------------------
__global__ void diag_kernel(float* out, float val) { out[0] = val; }

extern "C" void kernel_launch(void* const* d_in, const int* in_sizes, int n_in,
                              void* d_out, int out_size, void* d_ws,
                              size_t ws_size, hipStream_t stream) {
  const float* hidden = (const float*)d_in[1];
  const float* residual = (const float*)d_in[2];
  const float* ln_in_w = (const float*)d_in[3];
  const float* ln_post_w = (const float*)d_in[4];
  const float* Wqkvz = (const float*)d_in[5];
  const float* Wba = (const float*)d_in[6];
  const float* conv_w = (const float*)d_in[7];
  const float* A_log = (const float*)d_in[8];
  const float* dt_bias = (const float*)d_in[9];
  const float* norm_w = (const float*)d_in[10];
  const float* Wout = (const float*)d_in[11];
  const float* Wgate = (const float*)d_in[12];
  const float* Wup = (const float*)d_in[13];
  const float* Wdown = (const float*)d_in[14];

  char* ws = (char*)d_ws;
  size_t off = 0;
  auto alloc = [&](size_t n) {
    char* p = ws + off;
    off = (off + n + 255) & ~(size_t)255;
    return p;
  };
  u16* wslot = (u16*)alloc((size_t)INTER * DMODEL * 2);
  u16* hb = (u16*)alloc((size_t)BT * DMODEL * 2);
  u16* qkvb = (u16*)alloc((size_t)BT * CONVC * 2);
  u16* zb = (u16*)alloc((size_t)BT * VALDIM * 2);
  u16* qkvc = (u16*)alloc((size_t)BT * CONVC * 2);
  float* ba = (float*)alloc((size_t)BT * 64 * 4);
  float* bdpack = (float*)alloc((size_t)64 * 1024 * 2 * 4);
  u16* obf = (u16*)alloc((size_t)BT * VALDIM * 2);
  if (off > ws_size) {
    diag_kernel<<<1, 1, 0, stream>>>((float*)d_out, (float)(ws_size >> 20));
    return;
  }

  float* res1 = (float*)d_out;
  float* attn = (float*)d_out + (size_t)BT * DMODEL;
  float* res2 = attn;
  u16* h2b = hb;
  u16* gbuf = qkvc;
  u16* mbuf = qkvb;
  float* outp = (float*)d_out;

  u16* Tg = qkvb;
  u16* Pg = qkvb + (size_t)1024 * 4096;
  u16* KtTg = qkvb + (size_t)2 * 1024 * 4096;
  float* Bvec = ba;

  float* pWout = (float*)qkvb;  // 2 x 2048x2048 f32 (qkvb dead)
  float* pDown = (float*)zb;    // 4 x 2048x2048 f32 (zb..obf dead)

  dim3 blk(256);
  dim3 blk512(512);

  // 1. res1 = hidden+residual; hb = rmsnorm(res1)
  resnorm_kernel<<<BT, blk, 0, stream>>>(hidden, residual, ln_in_w, res1, hb);

  // 2. qkv-slice GEMM (256-tile 4-phase pipeline)
  convert_transpose<<<dim3(CONVC / 32, DMODEL / 32), blk, 0, stream>>>(
      Wqkvz, QKVZ_N, wslot, DMODEL, CONVC);
  gemm256_kernel<1><<<dim3(CONVC / 256, BT / 256), blk512, 0, stream>>>(
      hb, wslot, qkvb, nullptr, BT, CONVC, DMODEL, DMODEL);

  // 3. z-slice GEMM (128-tile)
  convert_transpose<<<dim3(VALDIM / 32, DMODEL / 32), blk, 0, stream>>>(
      Wqkvz + CONVC, QKVZ_N, wslot, DMODEL, VALDIM);
  gemm_kernel<1><<<dim3(VALDIM / 128, BT / 128), blk, 0, stream>>>(
      hb, wslot, zb, nullptr, BT, VALDIM, DMODEL, DMODEL);

  // 4. ba = hb @ Wba
  ba_gemm_kernel<<<BT, blk, 0, stream>>>(hb, Wba, ba);

  // 5-7. conv+silu, l2norm(q,k), beta/decay
  conv_silu_kernel<<<BT * 2048 / 256, blk, 0, stream>>>(qkvb, conv_w, qkvc);
  l2norm_kernel<<<BT * 32 / 4, blk, 0, stream>>>(qkvc);
  betadecay_kernel<<<BT * HV / 256, blk, 0, stream>>>(ba, A_log, dt_bias,
                                                      bdpack);

  // 8. chunked gated delta rule scan
  prep_kernel<<<dim3(16, 64), blk, 0, stream>>>(qkvc, bdpack, Tg, Pg, KtTg,
                                                Bvec);
  chunk_scan_kernel<<<dim3(4, 64), dim3(512), 0, stream>>>(
      qkvc, bdpack, Tg, Pg, KtTg, Bvec, obf);

  // 9. gate + per-head RMSNorm (in place over zb)
  gatenorm_kernel<<<BT * HV / 4, blk, 0, stream>>>(obf, zb, norm_w);

  // 10. attn = og @ Wout (128-tile, split-K=2, partials in dead qkvb)
  convert_transpose<<<dim3(DMODEL / 32, VALDIM / 32), blk, 0, stream>>>(
      Wout, DMODEL, wslot, VALDIM, DMODEL);
  gemm_kernel<0><<<dim3(DMODEL / 128, BT / 128, 2), blk, 0, stream>>>(
      zb, wslot, pWout, nullptr, BT, DMODEL, VALDIM, VALDIM / 2);
  reduce_kernel<<<BT * DMODEL / 1024, blk, 0, stream>>>(pWout, attn,
                                                        BT * DMODEL, 2);

  // 11. res2 = attn + res1; h2b = rmsnorm(res2)
  resnorm_kernel<<<BT, blk, 0, stream>>>(attn, res1, ln_post_w, res2, h2b);

  // 12. gate GEMM (256-tile 4-phase)
  convert_transpose<<<dim3(INTER / 32, DMODEL / 32), blk, 0, stream>>>(
      Wgate, INTER, wslot, DMODEL, INTER);
  gemm256_kernel<1><<<dim3(INTER / 256, BT / 256), blk512, 0, stream>>>(
      h2b, wslot, gbuf, nullptr, BT, INTER, DMODEL, DMODEL);

  // 13. up GEMM fused with m = silu(g)*u (256-tile 4-phase)
  convert_transpose<<<dim3(INTER / 32, DMODEL / 32), blk, 0, stream>>>(
      Wup, INTER, wslot, DMODEL, INTER);
  gemm256_kernel<2><<<dim3(INTER / 256, BT / 256), blk512, 0, stream>>>(
      h2b, wslot, mbuf, gbuf, BT, INTER, DMODEL, DMODEL);

  // 14. out = m @ Wdown (256-tile 4-phase, split-K=4)
  convert_transpose<<<dim3(DMODEL / 32, INTER / 32), blk, 0, stream>>>(
      Wdown, DMODEL, wslot, INTER, DMODEL);
  gemm256_kernel<0><<<dim3(DMODEL / 256, BT / 256, 4), blk512, 0, stream>>>(
      mbuf, wslot, pDown, nullptr, BT, DMODEL, INTER, INTER / 4);
  reduce_kernel<<<BT * DMODEL / 1024, blk, 0, stream>>>(pDown, outp,
                                                        BT * DMODEL, 4);
}

// Round 12
// 783.155 us; speedup vs baseline: 1.3153x; 1.0532x over previous
//
#include <hip/hip_runtime.h>
#include <hip/hip_bf16.h>

typedef unsigned short u16;
typedef unsigned int u32;
typedef float f32x4 __attribute__((ext_vector_type(4)));
typedef short bf16x8 __attribute__((ext_vector_type(8)));
typedef unsigned short u16x4 __attribute__((ext_vector_type(4)));
typedef unsigned int u32x2 __attribute__((ext_vector_type(2)));
typedef unsigned int u32x4 __attribute__((ext_vector_type(4)));

#define BT 2048            // B*T
#define DMODEL 2048
#define HV 32
#define DK 128
#define KEYDIM 2048
#define VALDIM 4096
#define QKVZ_N 12288
#define CONVC 8192         // q,k,v channels
#define INTER 8192

__device__ __forceinline__ float bf2f(u16 v) {
  u32 u = ((u32)v) << 16;
  return __builtin_bit_cast(float, u);
}
__device__ __forceinline__ u16 f2bf(float f) {
  u32 u = __builtin_bit_cast(u32, f);
  u32 r = (u + 0x7fffu + ((u >> 16) & 1u)) >> 16;
  return (u16)r;
}
__device__ __forceinline__ u32 pack2(float a, float b) {
  return (u32)f2bf(a) | ((u32)f2bf(b) << 16);
}
__device__ __forceinline__ float siluf(float x) {
  return x / (1.f + expf(-x));
}

// -------- weight convert+transpose: W[K,N] f32 (row stride ldw) -> Wt[N,K] bf16
__global__ __launch_bounds__(256) void convert_transpose(
    const float* __restrict__ W, int ldw, u16* __restrict__ Wt, int K, int N) {
  __shared__ float tile[32][33];
  int n0 = blockIdx.x * 32, k0 = blockIdx.y * 32;
  int tx = threadIdx.x & 31, ty = threadIdx.x >> 5;  // ty 0..7
#pragma unroll
  for (int i = 0; i < 4; ++i) {
    int kk = ty + i * 8;
    tile[kk][tx] = W[(size_t)(k0 + kk) * ldw + n0 + tx];
  }
  __syncthreads();
#pragma unroll
  for (int i = 0; i < 4; ++i) {
    int nn = ty + i * 8;
    Wt[(size_t)(n0 + nn) * K + k0 + tx] = f2bf(tile[tx][nn]);
  }
}

// -------- fused residual add + gemma RMSNorm (a+b -> resout f32, norm -> bf16)
__global__ __launch_bounds__(256) void resnorm_kernel(
    const float* __restrict__ a, const float* __restrict__ b,
    const float* __restrict__ w, float* __restrict__ resout,
    u16* __restrict__ hb) {
  int tok = blockIdx.x, t = threadIdx.x;
  const float* ap = a + (size_t)tok * DMODEL + t * 8;
  const float* bp = b + (size_t)tok * DMODEL + t * 8;
  f32x4 x0 = *(const f32x4*)ap + *(const f32x4*)bp;
  f32x4 x1 = *(const f32x4*)(ap + 4) + *(const f32x4*)(bp + 4);
  *(f32x4*)(resout + (size_t)tok * DMODEL + t * 8) = x0;
  *(f32x4*)(resout + (size_t)tok * DMODEL + t * 8 + 4) = x1;
  float ss = 0.f;
#pragma unroll
  for (int j = 0; j < 4; ++j) ss += x0[j] * x0[j] + x1[j] * x1[j];
#pragma unroll
  for (int m = 1; m < 64; m <<= 1) ss += __shfl_xor(ss, m, 64);
  __shared__ float red[4];
  if ((t & 63) == 0) red[t >> 6] = ss;
  __syncthreads();
  ss = red[0] + red[1] + red[2] + red[3];
  float sc = rsqrtf(ss * (1.f / (float)DMODEL) + 1e-6f);
  const float* wp = w + t * 8;
  float y[8];
#pragma unroll
  for (int j = 0; j < 4; ++j) {
    y[j] = x0[j] * sc * (1.f + wp[j]);
    y[4 + j] = x1[j] * sc * (1.f + wp[4 + j]);
  }
  u32x4 st;
  st[0] = pack2(y[0], y[1]);
  st[1] = pack2(y[2], y[3]);
  st[2] = pack2(y[4], y[5]);
  st[3] = pack2(y[6], y[7]);
  *(u32x4*)(hb + (size_t)tok * DMODEL + t * 8) = st;
}

__device__ __forceinline__ void async16(const void* g, void* l) {
  __builtin_amdgcn_global_load_lds(
      (const __attribute__((address_space(1))) u32*)g,
      (__attribute__((address_space(3))) u32*)l, 16, 0, 0);
}

// -------- 128-tile MFMA GEMM (proven round-8): ring-4, counted vmcnt --------
template <int OUT>
__global__ __launch_bounds__(256) void gemm_kernel(
    const u16* __restrict__ A, const u16* __restrict__ Bt,
    void* __restrict__ Cv, const u16* __restrict__ Aux, int M, int N,
    int Kfull, int Ks) {
  __shared__ __align__(16) u16 Al[4][128 * 32];
  __shared__ __align__(16) u16 Bl[4][128 * 32];
  int tid = threadIdx.x;
  int w = tid >> 6, l = tid & 63;
  int wr = w >> 1, wc = w & 1;
  int r15 = l & 15, kb = l >> 4;

  int nbx = gridDim.x, nby = gridDim.y;
  int bid = blockIdx.y * nbx + blockIdx.x;
  int nwg = nbx * nby;
  int cpx = nwg >> 3;
  int wg = (bid & 7) * cpx + (bid >> 3);
  const int GRP = 4;
  int span = GRP * nby;
  int grpId = wg / span;
  int rem = wg - grpId * span;
  int n0 = (grpId * GRP + (rem % GRP)) * 128;
  int m0 = (rem / GRP) * 128;
  int kbase = blockIdx.z * Ks;

  f32x4 acc[4][4] = {};

  auto stage = [&](int buf, int kt) {
#pragma unroll
    for (int c = 0; c < 2; ++c) {
      int gid = w * 128 + c * 64 + l;
      int row = gid >> 2;
      int g = (gid & 3) ^ ((row >> 1) & 3);
      async16(A + (size_t)(m0 + row) * Kfull + kt + g * 8, Al[buf] + gid * 8);
      async16(Bt + (size_t)(n0 + row) * Kfull + kt + g * 8, Bl[buf] + gid * 8);
    }
  };

  int nst = Ks >> 5;
#pragma unroll
  for (int p = 0; p < 3; ++p)
    if (p < nst) stage(p & 3, kbase + p * 32);

  for (int i = 0; i < nst; ++i) {
    int issued = (i + 3 < nst) ? (i + 3) : nst;
    int infl = issued - i - 1;
    if (infl >= 2)
      asm volatile("s_waitcnt vmcnt(8)" ::: "memory");
    else if (infl == 1)
      asm volatile("s_waitcnt vmcnt(4)" ::: "memory");
    else
      asm volatile("s_waitcnt vmcnt(0)" ::: "memory");
    __builtin_amdgcn_s_barrier();
    __builtin_amdgcn_sched_barrier(0);
    if (i + 3 < nst) stage((i + 3) & 3, kbase + (i + 3) * 32);
    const u16* Ac = Al[i & 3];
    const u16* Bc = Bl[i & 3];
    bf16x8 aF[4], bF[4];
#pragma unroll
    for (int m = 0; m < 4; ++m) {
      int row = wr * 64 + m * 16 + r15;
      aF[m] = *(const bf16x8*)(Ac + row * 32 + (kb ^ ((row >> 1) & 3)) * 8);
    }
#pragma unroll
    for (int n = 0; n < 4; ++n) {
      int row = wc * 64 + n * 16 + r15;
      bF[n] = *(const bf16x8*)(Bc + row * 32 + (kb ^ ((row >> 1) & 3)) * 8);
    }
#pragma unroll
    for (int m = 0; m < 4; ++m)
#pragma unroll
      for (int n = 0; n < 4; ++n)
        acc[m][n] = __builtin_amdgcn_mfma_f32_16x16x32_bf16(aF[m], bF[n],
                                                            acc[m][n], 0, 0, 0);
  }

  float* Cf = (float*)Cv + (size_t)blockIdx.z * M * N;
#pragma unroll
  for (int m = 0; m < 4; ++m)
#pragma unroll
    for (int n = 0; n < 4; ++n) {
      size_t base = (size_t)(m0 + wr * 64 + m * 16 + kb * 4) * N +
                    (n0 + wc * 64 + n * 16 + r15);
#pragma unroll
      for (int r = 0; r < 4; ++r) {
        size_t idx = base + (size_t)r * N;
        if (OUT == 0)
          Cf[idx] = acc[m][n][r];
        else if (OUT == 1)
          ((u16*)Cv)[idx] = f2bf(acc[m][n][r]);
        else
          ((u16*)Cv)[idx] = f2bf(siluf(bf2f(Aux[idx])) * acc[m][n][r]);
      }
    }
}

// -------- 256-tile 4-phase deep-pipeline GEMM (m201-style, BK=64, 512 thr) --
#define GPHASE(ACHUNK, BCHUNK, Q, READ_B, ST_OP, ST_KH, TAILVM)              \
  {                                                                          \
    if (READ_B) {                                                            \
      _Pragma("unroll") for (int n = 0; n < 4; ++n) {                        \
        int row = wn * 64 + n * 16 + r15;                                    \
        bF[n] = *(const bf16x8*)((BCHUNK) + row * 32 +                       \
                                 (kb ^ ((row >> 1) & 3)) * 8);               \
      }                                                                      \
    }                                                                        \
    _Pragma("unroll") for (int mm = 0; mm < 4; ++mm) {                       \
      int row = wm * 128 + (Q)*64 + mm * 16 + r15;                           \
      aF[mm] = *(const bf16x8*)((ACHUNK) + row * 32 +                        \
                                (kb ^ ((row >> 1) & 3)) * 8);                \
    }                                                                        \
    if (hn) stage(buf ^ 1, ST_OP, ST_KH, nc);                                \
    __builtin_amdgcn_s_barrier();                                            \
    asm volatile("s_waitcnt lgkmcnt(0)" ::: "memory");                       \
    __builtin_amdgcn_sched_barrier(0);                                       \
    __builtin_amdgcn_s_setprio(1);                                           \
    _Pragma("unroll") for (int mm = 0; mm < 4; ++mm)                         \
        _Pragma("unroll") for (int n = 0; n < 4; ++n)                        \
            acc[(Q)*4 + mm][n] = __builtin_amdgcn_mfma_f32_16x16x32_bf16(    \
                aF[mm], bF[n], acc[(Q)*4 + mm][n], 0, 0, 0);                 \
    __builtin_amdgcn_s_setprio(0);                                           \
    if (TAILVM) {                                                            \
      if (hn)                                                                \
        asm volatile("s_waitcnt vmcnt(4)" ::: "memory");                     \
      else                                                                   \
        asm volatile("s_waitcnt vmcnt(0)" ::: "memory");                     \
    }                                                                        \
    __builtin_amdgcn_s_barrier();                                            \
  }

template <int OUT>
__global__ __launch_bounds__(512, 2) void gemm256_kernel(
    const u16* __restrict__ A, const u16* __restrict__ Bt,
    void* __restrict__ Cv, const u16* __restrict__ Aux, int M, int N,
    int Kfull, int Ks) {
  __shared__ __align__(16) u16 S[65536];  // 128 KB: [buf][op][kh][256][32]
  int tid = threadIdx.x;
  int l = tid & 63, w = tid >> 6;
  int wm = w >> 2, wn = w & 3;  // 2M x 4N waves; wave tile 128(M) x 64(N)
  int r15 = l & 15, kb = l >> 4;

  int nbx = gridDim.x, nby = gridDim.y;  // N/256, M/256
  int bid = blockIdx.y * nbx + blockIdx.x;
  int nwg = nbx * nby;
  int cpx = nwg >> 3;
  int wg = (bid & 7) * cpx + (bid >> 3);
  const int GRP = 4;
  int span = GRP * nby;
  int grpId = wg / span;
  int rem = wg - grpId * span;
  int n0 = (grpId * GRP + (rem % GRP)) * 256;
  int m0 = (rem / GRP) * 128 * 2;
  int kbase = blockIdx.z * Ks;

  f32x4 acc[8][4] = {};

  // stage one 16KB unit: (op, kh) of K-tile at col base ktcol into buf
  auto stage = [&](int buf, int op, int kh, int ktcol) {
#pragma unroll
    for (int c = 0; c < 2; ++c) {
      int gid = c * 512 + tid;  // 1024 granules = 256 rows x 4
      int row = gid >> 2, gg = gid & 3;
      int gl = gg ^ ((row >> 1) & 3);
      const u16* src = (op == 0 ? A + (size_t)(m0 + row) * Kfull
                                : Bt + (size_t)(n0 + row) * Kfull) +
                       ktcol + kh * 32 + gl * 8;
      async16(src, S + ((buf * 2 + op) * 2 + kh) * 8192 + gid * 8);
    }
  };

  int nt = Ks >> 6;  // K-tiles of 64 (all call sites: nt = 32)
  // prologue: tile 0, units in steady-state order Akh0,Bkh0,Akh1,Bkh1
  stage(0, 0, 0, kbase);
  stage(0, 1, 0, kbase);
  stage(0, 0, 1, kbase);
  stage(0, 1, 1, kbase);
  asm volatile("s_waitcnt vmcnt(4)" ::: "memory");  // kh0 pair ready
  __builtin_amdgcn_s_barrier();

  for (int t = 0; t < nt; ++t) {
    int buf = t & 1;
    bool hn = t + 1 < nt;
    int nc = kbase + (t + 1) * 64;
    const u16* Ac0 = S + ((buf * 2 + 0) * 2 + 0) * 8192;
    const u16* Ac1 = S + ((buf * 2 + 0) * 2 + 1) * 8192;
    const u16* Bc0 = S + ((buf * 2 + 1) * 2 + 0) * 8192;
    const u16* Bc1 = S + ((buf * 2 + 1) * 2 + 1) * 8192;
    bf16x8 aF[4], bF[4];
    GPHASE(Ac0, Bc0, 0, true, 0, 0, false)   // ks0 q0; stage A kh0 (t+1)
    GPHASE(Ac0, Bc0, 1, false, 1, 0, true)   // ks0 q1; stage B kh0; vmcnt(4)
    GPHASE(Ac1, Bc1, 0, true, 0, 1, false)   // ks1 q0; stage A kh1 (t+1)
    GPHASE(Ac1, Bc1, 1, false, 1, 1, true)   // ks1 q1; stage B kh1; vmcnt(4)
  }

  float* Cf = (float*)Cv + (size_t)blockIdx.z * M * N;
#pragma unroll
  for (int m = 0; m < 8; ++m)
#pragma unroll
    for (int n = 0; n < 4; ++n) {
      size_t base = (size_t)(m0 + wm * 128 + m * 16 + kb * 4) * N +
                    (n0 + wn * 64 + n * 16 + r15);
#pragma unroll
      for (int r = 0; r < 4; ++r) {
        size_t idx = base + (size_t)r * N;
        if (OUT == 0)
          Cf[idx] = acc[m][n][r];
        else if (OUT == 1)
          ((u16*)Cv)[idx] = f2bf(acc[m][n][r]);
        else
          ((u16*)Cv)[idx] = f2bf(siluf(bf2f(Aux[idx])) * acc[m][n][r]);
      }
    }
}

// -------- split-K reduce: out[i] = sum_s parts[s*n + i] ---------------------
__global__ __launch_bounds__(256) void reduce_kernel(
    const float* __restrict__ p, float* __restrict__ o, int n, int S) {
  int i = (blockIdx.x * 256 + threadIdx.x) * 4;
  f32x4 s = *(const f32x4*)(p + i);
  for (int j = 1; j < S; ++j) s += *(const f32x4*)(p + (size_t)j * n + i);
  *(f32x4*)(o + i) = s;
}

// -------- ba = hb(bf16) @ Wba(f32 [2048,64]) --------------------------------
__global__ __launch_bounds__(256) void ba_gemm_kernel(
    const u16* __restrict__ hb, const float* __restrict__ Wba,
    float* __restrict__ ba) {
  int m = blockIdx.x;
  int t = threadIdx.x;
  int n = t & 63, kq = t >> 6;
  const u16* a = hb + (size_t)m * DMODEL + kq * 512;
  const float* wp = Wba + (size_t)kq * 512 * 64 + n;
  float sum = 0.f;
  for (int i = 0; i < 512; ++i)
    sum += bf2f(a[i]) * wp[(size_t)i * 64];
  __shared__ float red[256];
  red[t] = sum;
  __syncthreads();
  if (t < 64)
    ba[(size_t)m * 64 + t] = red[t] + red[t + 64] + red[t + 128] + red[t + 192];
}

// -------- causal depthwise conv (K=4) + SiLU, bf16 in/out -------------------
__global__ __launch_bounds__(256) void conv_silu_kernel(
    const u16* __restrict__ qkvb, const float* __restrict__ conv_w,
    u16* __restrict__ qkv) {
  int gid = blockIdx.x * 256 + threadIdx.x;
  int c4 = (gid & 2047) * 4;
  int bt = gid >> 11;
  int b = bt >> 10, tt = bt & 1023;
  f32x4 wv[4];
#pragma unroll
  for (int j = 0; j < 4; ++j) wv[j] = *(const f32x4*)(conv_w + (c4 + j) * 4);
  float acc[4] = {0.f, 0.f, 0.f, 0.f};
#pragma unroll
  for (int i = 0; i < 4; ++i) {
    int ts = tt - 3 + i;
    if (ts >= 0) {
      u16x4 x = *(const u16x4*)(qkvb + (size_t)(b * 1024 + ts) * CONVC + c4);
#pragma unroll
      for (int j = 0; j < 4; ++j) acc[j] += bf2f(x[j]) * wv[j][i];
    }
  }
  u32x2 st;
  st[0] = pack2(siluf(acc[0]), siluf(acc[1]));
  st[1] = pack2(siluf(acc[2]), siluf(acc[3]));
  *(u32x2*)(qkv + (size_t)bt * CONVC + c4) = st;
}

// -------- l2 norm of q,k heads in place (bf16), q also * DK^-0.5 ------------
__global__ __launch_bounds__(256) void l2norm_kernel(u16* __restrict__ qkv) {
  int wid = blockIdx.x * 4 + (threadIdx.x >> 6);
  int l = threadIdx.x & 63;
  int tok = wid >> 5, slot = wid & 31;
  u16* p = qkv + (size_t)tok * CONVC + slot * 128 + l * 2;
  float x0 = bf2f(p[0]), x1 = bf2f(p[1]);
  float ss = x0 * x0 + x1 * x1;
#pragma unroll
  for (int m = 1; m < 64; m <<= 1) ss += __shfl_xor(ss, m, 64);
  float sc = rsqrtf(ss + 1e-6f);
  if (slot < 16) sc *= 0.08838834764831845f;  // DK^-0.5
  *(u32*)p = pack2(x0 * sc, x1 * sc);
}

// -------- bd[(b*32+h)][t][2] = {sigmoid(bb), exp(-exp(A_log)*softplus)} -----
__global__ __launch_bounds__(256) void betadecay_kernel(
    const float* __restrict__ ba, const float* __restrict__ A_log,
    const float* __restrict__ dt_bias, float* __restrict__ bd) {
  int idx = blockIdx.x * 256 + threadIdx.x;
  int h = idx & 31;
  int tok = idx >> 5;
  int b = tok >> 10, tt = tok & 1023;
  float bb = ba[(size_t)tok * 64 + h];
  float aa = ba[(size_t)tok * 64 + 32 + h];
  float bet = 1.f / (1.f + expf(-bb));
  float x = aa + dt_bias[h];
  float sp = (x > 20.f) ? x : log1pf(expf(x));
  float dec = expf(-expf(A_log[h]) * sp);
  size_t o = (((size_t)(b * 32 + h)) * 1024 + tt) * 2;
  bd[o] = bet;
  bd[o + 1] = dec;
}

// ======================= chunked delta-rule scan ============================
// prep: register-resident forward substitution (no Tf LDS, no serial LDS
// chain); Af padded to stride 65; shuffle prefix-scan; sc63 precomputed.
__global__ __launch_bounds__(256) void prep_kernel(
    const u16* __restrict__ qkvc, const float* __restrict__ bdpack,
    u16* __restrict__ Tg, u16* __restrict__ Pg, u16* __restrict__ KtTg,
    float* __restrict__ Bvec) {
  __shared__ __align__(16) u16 Kl[64 * 128];
  __shared__ __align__(16) u16 Ql[64 * 128];
  __shared__ __align__(16) float Af[64 * 65];
  __shared__ float bl[64], betal[64], sc63[64];
  int tid = threadIdx.x;
  int w = tid >> 6, l = tid & 63;
  int r15 = l & 15, kb = l >> 4;
  int c = blockIdx.x, bh = blockIdx.y;
  int b = bh >> 5, h = bh & 31, hk = h >> 1;
  size_t tok0 = (size_t)b * 1024 + c * 64;
  int ch = bh * 16 + c;

  // stage K, Q tiles [64][128] bf16
#pragma unroll
  for (int rep = 0; rep < 4; ++rep) {
    int gid = w * 256 + rep * 64 + l;
    int row = gid >> 4, seg = gid & 15;
    const u16* srcq = qkvc + (tok0 + row) * CONVC + hk * 128 + seg * 8;
    async16(srcq, Ql + gid * 8);
    async16(srcq + KEYDIM, Kl + gid * 8);
  }
  // beta, log-decay, shuffle prefix scan, totals (wave 0 only)
  if (tid < 64) {
    size_t o = ((size_t)bh * 1024 + c * 64 + tid) * 2;
    betal[tid] = bdpack[o];
    float s = logf(fmaxf(bdpack[o + 1], 1e-30f));
#pragma unroll
    for (int d = 1; d < 64; d <<= 1) {
      float t = __shfl_up(s, d, 64);
      if (tid >= d) s += t;
    }
    bl[tid] = s;
    float tot = __shfl(s, 63, 64);
    sc63[tid] = expf(tot - s);
    Bvec[(size_t)ch * 64 + tid] = expf(s);
  }
  __syncthreads();

  // KK^T -> Af (stride 65, zero for j>=i); QK^T -> Pg (bf16)
  {
    f32x4 akk[4] = {}, aqk[4] = {};
#pragma unroll
    for (int ks = 0; ks < 4; ++ks) {
      bf16x8 kaF = *(const bf16x8*)(Kl + (w * 16 + r15) * 128 + ks * 32 + kb * 8);
      bf16x8 qaF = *(const bf16x8*)(Ql + (w * 16 + r15) * 128 + ks * 32 + kb * 8);
#pragma unroll
      for (int n = 0; n < 4; ++n) {
        bf16x8 bF = *(const bf16x8*)(Kl + (n * 16 + r15) * 128 + ks * 32 + kb * 8);
        akk[n] = __builtin_amdgcn_mfma_f32_16x16x32_bf16(kaF, bF, akk[n], 0, 0, 0);
        aqk[n] = __builtin_amdgcn_mfma_f32_16x16x32_bf16(qaF, bF, aqk[n], 0, 0, 0);
      }
    }
#pragma unroll
    for (int n = 0; n < 4; ++n)
#pragma unroll
      for (int r = 0; r < 4; ++r) {
        int i = w * 16 + kb * 4 + r;
        int j = n * 16 + r15;
        float e = expf(bl[i] - bl[j]);  // used only when j<=i (<=0 exponent)
        Af[i * 65 + j] = (j < i) ? betal[i] * e * akk[n][r] : 0.f;
        u16 pv = (j <= i) ? f2bf(e * aqk[n][r]) : (u16)0;
        Pg[(size_t)ch * 4096 + i * 64 + j] = pv;
      }
  }
  // KtT[d][j] = sc63[j] * K[j][d]  (bf16 global [128][64])
  for (int m = 0; m < 32; ++m) {
    int idx = tid * 32 + m;
    int d = idx >> 6, j = idx & 63;
    KtTg[(size_t)ch * 8192 + idx] = f2bf(bf2f(Kl[j * 128 + d]) * sc63[j]);
  }
  __syncthreads();  // Af fully written

  // register-resident forward substitution: T = (I+A)^-1
  // lane (kb,r15) of wave w holds tj[m] = T[4m+kb][ccol], ccol = w*16+r15.
  {
    int ccol = w * 16 + r15;
    float tj[16];
#pragma unroll
    for (int m = 0; m < 16; ++m) tj[m] = (4 * m + kb == ccol) ? 1.f : 0.f;
#pragma unroll
    for (int i = 1; i < 64; ++i) {
      float part = 0.f;
      const int mb = (i + 3) >> 2;  // uniform bound; Af zero for j>=i
#pragma unroll
      for (int m = 0; m < 16; ++m)
        if (m < mb) part = fmaf(Af[i * 65 + 4 * m + kb], tj[m], part);
      part += __shfl_xor(part, 16, 64);
      part += __shfl_xor(part, 32, 64);
      float nv = ((ccol == i) ? 1.f : 0.f) - part;
      if (kb == (i & 3)) tj[i >> 2] = nv;  // static index (i>>2 const)
    }
#pragma unroll
    for (int m = 0; m < 16; ++m)
      Tg[(size_t)ch * 4096 + (4 * m + kb) * 64 + ccol] = f2bf(tj[m]);
  }
}

__global__ __launch_bounds__(512) void chunk_scan_kernel(
    const u16* __restrict__ qkvc, const float* __restrict__ bdpack,
    const u16* __restrict__ Tg, const u16* __restrict__ Pg,
    const u16* __restrict__ KtTg, const float* __restrict__ Bvec,
    u16* __restrict__ obf) {
  __shared__ __align__(16) u16 Kl[64 * 128];
  __shared__ __align__(16) u16 Ql[64 * 128];
  __shared__ __align__(16) u16 KtTl[128 * 64];
  __shared__ __align__(16) u16 Tl[64 * 64];
  __shared__ __align__(16) u16 Pl[64 * 64];
  __shared__ __align__(16) u16 Vl[64 * 32];
  __shared__ __align__(16) u16 St[32 * 128];
  __shared__ __align__(16) u16 rhsT[32 * 64];
  __shared__ __align__(16) u16 dT[32 * 64];
  __shared__ float betal[64], Gl[64];

  int tid = threadIdx.x;
  int w = tid >> 6, l = tid & 63;
  int r15 = l & 15, kb = l >> 4;
  int dvc = blockIdx.x, bh = blockIdx.y;
  int b = bh >> 5, h = bh & 31, hk = h >> 1;
  int a = w >> 1, bcol = w & 1;

  for (int m = tid; m < 32 * 128; m += 512) St[m] = 0;
  f32x4 sAcc0 = {}, sAcc1 = {};
  __syncthreads();

  for (int c = 0; c < 16; ++c) {
    size_t tok0 = (size_t)b * 1024 + c * 64;
    int ch = bh * 16 + c;
#pragma unroll
    for (int rep = 0; rep < 2; ++rep) {
      int gid = w * 128 + rep * 64 + l;
      int row = gid >> 4, seg = gid & 15;
      const u16* srcq = qkvc + (tok0 + row) * CONVC + hk * 128 + seg * 8;
      async16(srcq, Ql + gid * 8);
      async16(srcq + KEYDIM, Kl + gid * 8);
      async16(KtTg + (size_t)ch * 8192 + gid * 8, KtTl + gid * 8);
    }
    {
      int gid = w * 64 + l;
      async16(Tg + (size_t)ch * 4096 + gid * 8, Tl + gid * 8);
      async16(Pg + (size_t)ch * 4096 + gid * 8, Pl + gid * 8);
    }
    if (w < 4) {
      int gid = w * 64 + l;
      int row = gid >> 2, seg = gid & 3;
      async16(qkvc + (tok0 + row) * CONVC + 2 * KEYDIM + h * 128 + dvc * 32 + seg * 8,
              Vl + gid * 8);
    }
    if (tid < 64) {
      betal[tid] = bdpack[((size_t)bh * 1024 + c * 64 + tid) * 2];
      Gl[tid] = Bvec[(size_t)ch * 64 + tid];
    }
    __syncthreads();

    f32x4 aKS = {}, aQS = {};
#pragma unroll
    for (int ks = 0; ks < 4; ++ks) {
      bf16x8 bF = *(const bf16x8*)(St + (bcol * 16 + r15) * 128 + ks * 32 + kb * 8);
      bf16x8 kF = *(const bf16x8*)(Kl + (a * 16 + r15) * 128 + ks * 32 + kb * 8);
      bf16x8 qF = *(const bf16x8*)(Ql + (a * 16 + r15) * 128 + ks * 32 + kb * 8);
      aKS = __builtin_amdgcn_mfma_f32_16x16x32_bf16(kF, bF, aKS, 0, 0, 0);
      aQS = __builtin_amdgcn_mfma_f32_16x16x32_bf16(qF, bF, aQS, 0, 0, 0);
    }
    {
      int i0 = a * 16 + kb * 4;
      int dv = bcol * 16 + r15;
      u16x4 st;
#pragma unroll
      for (int r = 0; r < 4; ++r) {
        int i = i0 + r;
        float v = bf2f(Vl[i * 32 + dv]);
        st[r] = f2bf(betal[i] * (v - Gl[i] * aKS[r]));
      }
      *(u16x4*)(rhsT + dv * 64 + i0) = st;
    }
    __syncthreads();
    f32x4 aD = {};
#pragma unroll
    for (int ks = 0; ks < 2; ++ks) {
      bf16x8 aF = *(const bf16x8*)(Tl + (a * 16 + r15) * 64 + ks * 32 + kb * 8);
      bf16x8 bF = *(const bf16x8*)(rhsT + (bcol * 16 + r15) * 64 + ks * 32 + kb * 8);
      aD = __builtin_amdgcn_mfma_f32_16x16x32_bf16(aF, bF, aD, 0, 0, 0);
    }
    {
      int i0 = a * 16 + kb * 4;
      int dv = bcol * 16 + r15;
      u16x4 st;
#pragma unroll
      for (int r = 0; r < 4; ++r) st[r] = f2bf(aD[r]);
      *(u16x4*)(dT + dv * 64 + i0) = st;
    }
    __syncthreads();
    f32x4 aO = {};
#pragma unroll
    for (int ks = 0; ks < 2; ++ks) {
      bf16x8 aF = *(const bf16x8*)(Pl + (a * 16 + r15) * 64 + ks * 32 + kb * 8);
      bf16x8 bF = *(const bf16x8*)(dT + (bcol * 16 + r15) * 64 + ks * 32 + kb * 8);
      aO = __builtin_amdgcn_mfma_f32_16x16x32_bf16(aF, bF, aO, 0, 0, 0);
    }
    {
      int i0 = a * 16 + kb * 4;
      int dv = bcol * 16 + r15;
#pragma unroll
      for (int r = 0; r < 4; ++r) {
        int i = i0 + r;
        float o = aO[r] + Gl[i] * aQS[r];
        obf[(tok0 + i) * VALDIM + h * 128 + dvc * 32 + dv] = f2bf(o);
      }
    }
    float gL = Gl[63];
#pragma unroll
    for (int r = 0; r < 4; ++r) { sAcc0[r] *= gL; sAcc1[r] *= gL; }
#pragma unroll
    for (int ks = 0; ks < 2; ++ks) {
      bf16x8 aF = *(const bf16x8*)(KtTl + (w * 16 + r15) * 64 + ks * 32 + kb * 8);
      bf16x8 b0 = *(const bf16x8*)(dT + r15 * 64 + ks * 32 + kb * 8);
      bf16x8 b1 = *(const bf16x8*)(dT + (16 + r15) * 64 + ks * 32 + kb * 8);
      sAcc0 = __builtin_amdgcn_mfma_f32_16x16x32_bf16(aF, b0, sAcc0, 0, 0, 0);
      sAcc1 = __builtin_amdgcn_mfma_f32_16x16x32_bf16(aF, b1, sAcc1, 0, 0, 0);
    }
#pragma unroll
    for (int r = 0; r < 4; ++r) {
      int dk = w * 16 + kb * 4 + r;
      St[r15 * 128 + dk] = f2bf(sAcc0[r]);
      St[(16 + r15) * 128 + dk] = f2bf(sAcc1[r]);
    }
    __syncthreads();
  }
}

// -------- gate (silu(z)) + per-head RMSNorm, in-place over z ----------------
__global__ __launch_bounds__(256) void gatenorm_kernel(
    const u16* __restrict__ obf, u16* __restrict__ zb,
    const float* __restrict__ norm_w) {
  int wid = blockIdx.x * 4 + (threadIdx.x >> 6);
  int l = threadIdx.x & 63;
  int tok = wid >> 5, h = wid & 31;
  const u16* op = obf + (size_t)tok * VALDIM + h * 128 + l * 2;
  u16* zp = zb + (size_t)tok * VALDIM + h * 128 + l * 2;
  float o0 = bf2f(op[0]), o1 = bf2f(op[1]);
  float z0 = bf2f(zp[0]), z1 = bf2f(zp[1]);
  float g0 = o0 * siluf(z0);
  float g1 = o1 * siluf(z1);
  float ss = g0 * g0 + g1 * g1;
#pragma unroll
  for (int m = 1; m < 64; m <<= 1) ss += __shfl_xor(ss, m, 64);
  float sc = rsqrtf(ss * (1.f / 128.f) + 1e-6f);
  int e = l * 2;
  *(u32*)zp = pack2(g0 * sc * norm_w[e], g1 * sc * norm_w[e + 1]);
}

// -------- diagnostic --------------------------------------------------------
__global__ void diag_kernel(float* out, float val) { out[0] = val; }

extern "C" void kernel_launch(void* const* d_in, const int* in_sizes, int n_in,
                              void* d_out, int out_size, void* d_ws,
                              size_t ws_size, hipStream_t stream) {
  const float* hidden = (const float*)d_in[1];
  const float* residual = (const float*)d_in[2];
  const float* ln_in_w = (const float*)d_in[3];
  const float* ln_post_w = (const float*)d_in[4];
  const float* Wqkvz = (const float*)d_in[5];
  const float* Wba = (const float*)d_in[6];
  const float* conv_w = (const float*)d_in[7];
  const float* A_log = (const float*)d_in[8];
  const float* dt_bias = (const float*)d_in[9];
  const float* norm_w = (const float*)d_in[10];
  const float* Wout = (const float*)d_in[11];
  const float* Wgate = (const float*)d_in[12];
  const float* Wup = (const float*)d_in[13];
  const float* Wdown = (const float*)d_in[14];

  char* ws = (char*)d_ws;
  size_t off = 0;
  auto alloc = [&](size_t n) {
    char* p = ws + off;
    off = (off + n + 255) & ~(size_t)255;
    return p;
  };
  u16* wslot = (u16*)alloc((size_t)INTER * DMODEL * 2);
  u16* hb = (u16*)alloc((size_t)BT * DMODEL * 2);
  u16* qkvb = (u16*)alloc((size_t)BT * CONVC * 2);
  u16* zb = (u16*)alloc((size_t)BT * VALDIM * 2);
  u16* qkvc = (u16*)alloc((size_t)BT * CONVC * 2);
  float* ba = (float*)alloc((size_t)BT * 64 * 4);
  float* bdpack = (float*)alloc((size_t)64 * 1024 * 2 * 4);
  u16* obf = (u16*)alloc((size_t)BT * VALDIM * 2);
  if (off > ws_size) {
    diag_kernel<<<1, 1, 0, stream>>>((float*)d_out, (float)(ws_size >> 20));
    return;
  }

  float* res1 = (float*)d_out;
  float* attn = (float*)d_out + (size_t)BT * DMODEL;
  float* res2 = attn;
  u16* h2b = hb;
  u16* gbuf = qkvc;
  u16* mbuf = qkvb;
  float* outp = (float*)d_out;

  u16* Tg = qkvb;
  u16* Pg = qkvb + (size_t)1024 * 4096;
  u16* KtTg = qkvb + (size_t)2 * 1024 * 4096;
  float* Bvec = ba;

  float* pWout = (float*)qkvb;  // 2 x 2048x2048 f32 (qkvb dead)
  float* pDown = (float*)zb;    // 4 x 2048x2048 f32 (zb..obf dead)

  dim3 blk(256);
  dim3 blk512(512);

  // 1. res1 = hidden+residual; hb = rmsnorm(res1)
  resnorm_kernel<<<BT, blk, 0, stream>>>(hidden, residual, ln_in_w, res1, hb);

  // 2. qkv-slice GEMM (256-tile 4-phase pipeline)
  convert_transpose<<<dim3(CONVC / 32, DMODEL / 32), blk, 0, stream>>>(
      Wqkvz, QKVZ_N, wslot, DMODEL, CONVC);
  gemm256_kernel<1><<<dim3(CONVC / 256, BT / 256), blk512, 0, stream>>>(
      hb, wslot, qkvb, nullptr, BT, CONVC, DMODEL, DMODEL);

  // 3. z-slice GEMM (128-tile)
  convert_transpose<<<dim3(VALDIM / 32, DMODEL / 32), blk, 0, stream>>>(
      Wqkvz + CONVC, QKVZ_N, wslot, DMODEL, VALDIM);
  gemm_kernel<1><<<dim3(VALDIM / 128, BT / 128), blk, 0, stream>>>(
      hb, wslot, zb, nullptr, BT, VALDIM, DMODEL, DMODEL);

  // 4. ba = hb @ Wba
  ba_gemm_kernel<<<BT, blk, 0, stream>>>(hb, Wba, ba);

  // 5-7. conv+silu, l2norm(q,k), beta/decay
  conv_silu_kernel<<<BT * 2048 / 256, blk, 0, stream>>>(qkvb, conv_w, qkvc);
  l2norm_kernel<<<BT * 32 / 4, blk, 0, stream>>>(qkvc);
  betadecay_kernel<<<BT * HV / 256, blk, 0, stream>>>(ba, A_log, dt_bias,
                                                      bdpack);

  // 8. chunked gated delta rule scan
  prep_kernel<<<dim3(16, 64), blk, 0, stream>>>(qkvc, bdpack, Tg, Pg, KtTg,
                                                Bvec);
  chunk_scan_kernel<<<dim3(4, 64), dim3(512), 0, stream>>>(
      qkvc, bdpack, Tg, Pg, KtTg, Bvec, obf);

  // 9. gate + per-head RMSNorm (in place over zb)
  gatenorm_kernel<<<BT * HV / 4, blk, 0, stream>>>(obf, zb, norm_w);

  // 10. attn = og @ Wout (128-tile, split-K=2, partials in dead qkvb)
  convert_transpose<<<dim3(DMODEL / 32, VALDIM / 32), blk, 0, stream>>>(
      Wout, DMODEL, wslot, VALDIM, DMODEL);
  gemm_kernel<0><<<dim3(DMODEL / 128, BT / 128, 2), blk, 0, stream>>>(
      zb, wslot, pWout, nullptr, BT, DMODEL, VALDIM, VALDIM / 2);
  reduce_kernel<<<BT * DMODEL / 1024, blk, 0, stream>>>(pWout, attn,
                                                        BT * DMODEL, 2);

  // 11. res2 = attn + res1; h2b = rmsnorm(res2)
  resnorm_kernel<<<BT, blk, 0, stream>>>(attn, res1, ln_post_w, res2, h2b);

  // 12. gate GEMM (256-tile 4-phase)
  convert_transpose<<<dim3(INTER / 32, DMODEL / 32), blk, 0, stream>>>(
      Wgate, INTER, wslot, DMODEL, INTER);
  gemm256_kernel<1><<<dim3(INTER / 256, BT / 256), blk512, 0, stream>>>(
      h2b, wslot, gbuf, nullptr, BT, INTER, DMODEL, DMODEL);

  // 13. up GEMM fused with m = silu(g)*u (256-tile 4-phase)
  convert_transpose<<<dim3(INTER / 32, DMODEL / 32), blk, 0, stream>>>(
      Wup, INTER, wslot, DMODEL, INTER);
  gemm256_kernel<2><<<dim3(INTER / 256, BT / 256), blk512, 0, stream>>>(
      h2b, wslot, mbuf, gbuf, BT, INTER, DMODEL, DMODEL);

  // 14. out = m @ Wdown (256-tile 4-phase, split-K=4)
  convert_transpose<<<dim3(DMODEL / 32, INTER / 32), blk, 0, stream>>>(
      Wdown, DMODEL, wslot, INTER, DMODEL);
  gemm256_kernel<0><<<dim3(DMODEL / 256, BT / 256, 4), blk512, 0, stream>>>(
      mbuf, wslot, pDown, nullptr, BT, DMODEL, INTER, INTER / 4);
  reduce_kernel<<<BT * DMODEL / 1024, blk, 0, stream>>>(pDown, outp,
                                                        BT * DMODEL, 4);
}

// Round 13
// 764.414 us; speedup vs baseline: 1.3475x; 1.0245x over previous
//
#include <hip/hip_runtime.h>
#include <hip/hip_bf16.h>

typedef unsigned short u16;
typedef unsigned int u32;
typedef float f32x4 __attribute__((ext_vector_type(4)));
typedef short bf16x8 __attribute__((ext_vector_type(8)));
typedef unsigned short u16x4 __attribute__((ext_vector_type(4)));
typedef unsigned int u32x2 __attribute__((ext_vector_type(2)));
typedef unsigned int u32x4 __attribute__((ext_vector_type(4)));

#define BT 2048            // B*T
#define DMODEL 2048
#define HV 32
#define DK 128
#define KEYDIM 2048
#define VALDIM 4096
#define QKVZ_N 12288
#define CONVC 8192         // q,k,v channels
#define INTER 8192

__device__ __forceinline__ float bf2f(u16 v) {
  u32 u = ((u32)v) << 16;
  return __builtin_bit_cast(float, u);
}
__device__ __forceinline__ u16 f2bf(float f) {
  u32 u = __builtin_bit_cast(u32, f);
  u32 r = (u + 0x7fffu + ((u >> 16) & 1u)) >> 16;
  return (u16)r;
}
__device__ __forceinline__ u32 pack2(float a, float b) {
  return (u32)f2bf(a) | ((u32)f2bf(b) << 16);
}
__device__ __forceinline__ float siluf(float x) {
  return x / (1.f + expf(-x));
}

// -------- weight convert+transpose: W[K,N] f32 -> Wt[N,K] bf16 --------------
// 64x64 tile, f32x4 vector loads, transposed-LDS (stride 68), u16x4 stores.
__global__ __launch_bounds__(256) void convert_transpose(
    const float* __restrict__ W, int ldw, u16* __restrict__ Wt, int K, int N) {
  __shared__ float tileT[64][68];  // [n][k], stride 68 (16B-aligned rows)
  int n0 = blockIdx.x * 64, k0 = blockIdx.y * 64;
  int tx = threadIdx.x & 15, ty = threadIdx.x >> 4;  // tx: 16x f32x4; ty: rows
#pragma unroll
  for (int i = 0; i < 4; ++i) {
    int kk = ty + i * 16;
    f32x4 v = *(const f32x4*)(W + (size_t)(k0 + kk) * ldw + n0 + tx * 4);
#pragma unroll
    for (int j = 0; j < 4; ++j) tileT[tx * 4 + j][kk] = v[j];
  }
  __syncthreads();
#pragma unroll
  for (int i = 0; i < 4; ++i) {
    int nn = ty + i * 16;
    f32x4 v = *(const f32x4*)(&tileT[nn][tx * 4]);
    u16x4 st;
#pragma unroll
    for (int j = 0; j < 4; ++j) st[j] = f2bf(v[j]);
    *(u16x4*)(Wt + (size_t)(n0 + nn) * K + k0 + tx * 4) = st;
  }
}

// -------- fused residual add + gemma RMSNorm (a+b -> resout f32, norm -> bf16)
__global__ __launch_bounds__(256) void resnorm_kernel(
    const float* __restrict__ a, const float* __restrict__ b,
    const float* __restrict__ w, float* __restrict__ resout,
    u16* __restrict__ hb) {
  int tok = blockIdx.x, t = threadIdx.x;
  const float* ap = a + (size_t)tok * DMODEL + t * 8;
  const float* bp = b + (size_t)tok * DMODEL + t * 8;
  f32x4 x0 = *(const f32x4*)ap + *(const f32x4*)bp;
  f32x4 x1 = *(const f32x4*)(ap + 4) + *(const f32x4*)(bp + 4);
  *(f32x4*)(resout + (size_t)tok * DMODEL + t * 8) = x0;
  *(f32x4*)(resout + (size_t)tok * DMODEL + t * 8 + 4) = x1;
  float ss = 0.f;
#pragma unroll
  for (int j = 0; j < 4; ++j) ss += x0[j] * x0[j] + x1[j] * x1[j];
#pragma unroll
  for (int m = 1; m < 64; m <<= 1) ss += __shfl_xor(ss, m, 64);
  __shared__ float red[4];
  if ((t & 63) == 0) red[t >> 6] = ss;
  __syncthreads();
  ss = red[0] + red[1] + red[2] + red[3];
  float sc = rsqrtf(ss * (1.f / (float)DMODEL) + 1e-6f);
  const float* wp = w + t * 8;
  float y[8];
#pragma unroll
  for (int j = 0; j < 4; ++j) {
    y[j] = x0[j] * sc * (1.f + wp[j]);
    y[4 + j] = x1[j] * sc * (1.f + wp[4 + j]);
  }
  u32x4 st;
  st[0] = pack2(y[0], y[1]);
  st[1] = pack2(y[2], y[3]);
  st[2] = pack2(y[4], y[5]);
  st[3] = pack2(y[6], y[7]);
  *(u32x4*)(hb + (size_t)tok * DMODEL + t * 8) = st;
}

// -------- resnorm over (p0 + p1 + b): fuses Wout split-K reduce -------------
__global__ __launch_bounds__(256) void resnorm2_kernel(
    const float* __restrict__ p, const float* __restrict__ b,
    const float* __restrict__ w, float* __restrict__ resout,
    u16* __restrict__ hb) {
  int tok = blockIdx.x, t = threadIdx.x;
  size_t base = (size_t)tok * DMODEL + t * 8;
  const float* p0 = p + base;
  const float* p1 = p + (size_t)BT * DMODEL + base;
  const float* bp = b + base;
  f32x4 x0 = *(const f32x4*)p0 + *(const f32x4*)p1 + *(const f32x4*)bp;
  f32x4 x1 = *(const f32x4*)(p0 + 4) + *(const f32x4*)(p1 + 4) +
             *(const f32x4*)(bp + 4);
  *(f32x4*)(resout + base) = x0;
  *(f32x4*)(resout + base + 4) = x1;
  float ss = 0.f;
#pragma unroll
  for (int j = 0; j < 4; ++j) ss += x0[j] * x0[j] + x1[j] * x1[j];
#pragma unroll
  for (int m = 1; m < 64; m <<= 1) ss += __shfl_xor(ss, m, 64);
  __shared__ float red[4];
  if ((t & 63) == 0) red[t >> 6] = ss;
  __syncthreads();
  ss = red[0] + red[1] + red[2] + red[3];
  float sc = rsqrtf(ss * (1.f / (float)DMODEL) + 1e-6f);
  const float* wp = w + t * 8;
  float y[8];
#pragma unroll
  for (int j = 0; j < 4; ++j) {
    y[j] = x0[j] * sc * (1.f + wp[j]);
    y[4 + j] = x1[j] * sc * (1.f + wp[4 + j]);
  }
  u32x4 st;
  st[0] = pack2(y[0], y[1]);
  st[1] = pack2(y[2], y[3]);
  st[2] = pack2(y[4], y[5]);
  st[3] = pack2(y[6], y[7]);
  *(u32x4*)(hb + base) = st;
}

__device__ __forceinline__ void async16(const void* g, void* l) {
  __builtin_amdgcn_global_load_lds(
      (const __attribute__((address_space(1))) u32*)g,
      (__attribute__((address_space(3))) u32*)l, 16, 0, 0);
}

// -------- 128-tile MFMA GEMM (proven round-8): ring-4, counted vmcnt --------
template <int OUT>
__global__ __launch_bounds__(256) void gemm_kernel(
    const u16* __restrict__ A, const u16* __restrict__ Bt,
    void* __restrict__ Cv, const u16* __restrict__ Aux, int M, int N,
    int Kfull, int Ks) {
  __shared__ __align__(16) u16 Al[4][128 * 32];
  __shared__ __align__(16) u16 Bl[4][128 * 32];
  int tid = threadIdx.x;
  int w = tid >> 6, l = tid & 63;
  int wr = w >> 1, wc = w & 1;
  int r15 = l & 15, kb = l >> 4;

  int nbx = gridDim.x, nby = gridDim.y;
  int bid = blockIdx.y * nbx + blockIdx.x;
  int nwg = nbx * nby;
  int cpx = nwg >> 3;
  int wg = (bid & 7) * cpx + (bid >> 3);
  const int GRP = 4;
  int span = GRP * nby;
  int grpId = wg / span;
  int rem = wg - grpId * span;
  int n0 = (grpId * GRP + (rem % GRP)) * 128;
  int m0 = (rem / GRP) * 128;
  int kbase = blockIdx.z * Ks;

  f32x4 acc[4][4] = {};

  // hoisted per-thread stage base pointers (advance via 32-bit koff)
  const u16* baseA[2];
  const u16* baseB[2];
#pragma unroll
  for (int c = 0; c < 2; ++c) {
    int gid = w * 128 + c * 64 + l;
    int row = gid >> 2;
    int g = (gid & 3) ^ ((row >> 1) & 3);
    baseA[c] = A + (size_t)(m0 + row) * Kfull + kbase + g * 8;
    baseB[c] = Bt + (size_t)(n0 + row) * Kfull + kbase + g * 8;
  }
  auto stage = [&](int buf, int koff) {
#pragma unroll
    for (int c = 0; c < 2; ++c) {
      int gid = w * 128 + c * 64 + l;
      async16(baseA[c] + koff, Al[buf] + gid * 8);
      async16(baseB[c] + koff, Bl[buf] + gid * 8);
    }
  };

  int nst = Ks >> 5;
#pragma unroll
  for (int p = 0; p < 3; ++p)
    if (p < nst) stage(p & 3, p * 32);

  for (int i = 0; i < nst; ++i) {
    int issued = (i + 3 < nst) ? (i + 3) : nst;
    int infl = issued - i - 1;
    if (infl >= 2)
      asm volatile("s_waitcnt vmcnt(8)" ::: "memory");
    else if (infl == 1)
      asm volatile("s_waitcnt vmcnt(4)" ::: "memory");
    else
      asm volatile("s_waitcnt vmcnt(0)" ::: "memory");
    __builtin_amdgcn_s_barrier();
    __builtin_amdgcn_sched_barrier(0);
    if (i + 3 < nst) stage((i + 3) & 3, (i + 3) * 32);
    const u16* Ac = Al[i & 3];
    const u16* Bc = Bl[i & 3];
    bf16x8 aF[4], bF[4];
#pragma unroll
    for (int m = 0; m < 4; ++m) {
      int row = wr * 64 + m * 16 + r15;
      aF[m] = *(const bf16x8*)(Ac + row * 32 + (kb ^ ((row >> 1) & 3)) * 8);
    }
#pragma unroll
    for (int n = 0; n < 4; ++n) {
      int row = wc * 64 + n * 16 + r15;
      bF[n] = *(const bf16x8*)(Bc + row * 32 + (kb ^ ((row >> 1) & 3)) * 8);
    }
#pragma unroll
    for (int m = 0; m < 4; ++m)
#pragma unroll
      for (int n = 0; n < 4; ++n)
        acc[m][n] = __builtin_amdgcn_mfma_f32_16x16x32_bf16(aF[m], bF[n],
                                                            acc[m][n], 0, 0, 0);
  }

  float* Cf = (float*)Cv + (size_t)blockIdx.z * M * N;
#pragma unroll
  for (int m = 0; m < 4; ++m)
#pragma unroll
    for (int n = 0; n < 4; ++n) {
      size_t base = (size_t)(m0 + wr * 64 + m * 16 + kb * 4) * N +
                    (n0 + wc * 64 + n * 16 + r15);
#pragma unroll
      for (int r = 0; r < 4; ++r) {
        size_t idx = base + (size_t)r * N;
        if (OUT == 0)
          Cf[idx] = acc[m][n][r];
        else if (OUT == 1)
          ((u16*)Cv)[idx] = f2bf(acc[m][n][r]);
        else
          ((u16*)Cv)[idx] = f2bf(siluf(bf2f(Aux[idx])) * acc[m][n][r]);
      }
    }
}

// -------- 256-tile 4-phase deep-pipeline GEMM (m201-style, BK=64, 512 thr) --
#define GPHASE(ACHUNK, BCHUNK, Q, READ_B, ST_OP, ST_KH, TAILVM)              \
  {                                                                          \
    if (READ_B) {                                                            \
      _Pragma("unroll") for (int n = 0; n < 4; ++n) {                        \
        int row = wn * 64 + n * 16 + r15;                                    \
        bF[n] = *(const bf16x8*)((BCHUNK) + row * 32 +                       \
                                 (kb ^ ((row >> 1) & 3)) * 8);               \
      }                                                                      \
    }                                                                        \
    _Pragma("unroll") for (int mm = 0; mm < 4; ++mm) {                       \
      int row = wm * 128 + (Q)*64 + mm * 16 + r15;                           \
      aF[mm] = *(const bf16x8*)((ACHUNK) + row * 32 +                        \
                                (kb ^ ((row >> 1) & 3)) * 8);                \
    }                                                                        \
    if (hn) stage(buf ^ 1, ST_OP, ST_KH, koff);                              \
    __builtin_amdgcn_s_barrier();                                            \
    asm volatile("s_waitcnt lgkmcnt(0)" ::: "memory");                       \
    __builtin_amdgcn_sched_barrier(0);                                       \
    __builtin_amdgcn_s_setprio(1);                                           \
    _Pragma("unroll") for (int mm = 0; mm < 4; ++mm)                         \
        _Pragma("unroll") for (int n = 0; n < 4; ++n)                        \
            acc[(Q)*4 + mm][n] = __builtin_amdgcn_mfma_f32_16x16x32_bf16(    \
                aF[mm], bF[n], acc[(Q)*4 + mm][n], 0, 0, 0);                 \
    __builtin_amdgcn_s_setprio(0);                                           \
    if (TAILVM) {                                                            \
      if (hn)                                                                \
        asm volatile("s_waitcnt vmcnt(4)" ::: "memory");                     \
      else                                                                   \
        asm volatile("s_waitcnt vmcnt(0)" ::: "memory");                     \
    }                                                                        \
    __builtin_amdgcn_s_barrier();                                            \
  }

template <int OUT>
__global__ __launch_bounds__(512, 2) void gemm256_kernel(
    const u16* __restrict__ A, const u16* __restrict__ Bt,
    void* __restrict__ Cv, const u16* __restrict__ Aux, int M, int N,
    int Kfull, int Ks) {
  __shared__ __align__(16) u16 S[65536];  // 128 KB: [buf][op][kh][256][32]
  int tid = threadIdx.x;
  int l = tid & 63, w = tid >> 6;
  int wm = w >> 2, wn = w & 3;  // 2M x 4N waves; wave tile 128(M) x 64(N)
  int r15 = l & 15, kb = l >> 4;

  int nbx = gridDim.x, nby = gridDim.y;  // N/256, M/256
  int bid = blockIdx.y * nbx + blockIdx.x;
  int nwg = nbx * nby;
  int cpx = nwg >> 3;
  int wg = (bid & 7) * cpx + (bid >> 3);
  const int GRP = 4;
  int span = GRP * nby;
  int grpId = wg / span;
  int rem = wg - grpId * span;
  int n0 = (grpId * GRP + (rem % GRP)) * 256;
  int m0 = (rem / GRP) * 256;
  int kbase = blockIdx.z * Ks;

  f32x4 acc[8][4] = {};

  // hoisted per-thread stage base pointers
  const u16* baseA[2];
  const u16* baseB[2];
#pragma unroll
  for (int c = 0; c < 2; ++c) {
    int gid = c * 512 + tid;
    int row = gid >> 2, gg = gid & 3;
    int gl = gg ^ ((row >> 1) & 3);
    baseA[c] = A + (size_t)(m0 + row) * Kfull + kbase + gl * 8;
    baseB[c] = Bt + (size_t)(n0 + row) * Kfull + kbase + gl * 8;
  }
  // stage one 16KB unit: (op, kh) of the K-tile at 32-bit offset koff
  auto stage = [&](int buf, int op, int kh, int koff) {
#pragma unroll
    for (int c = 0; c < 2; ++c) {
      int gid = c * 512 + tid;
      const u16* src = (op == 0 ? baseA[c] : baseB[c]) + koff + kh * 32;
      async16(src, S + ((buf * 2 + op) * 2 + kh) * 8192 + gid * 8);
    }
  };

  int nt = Ks >> 6;  // K-tiles of 64
  // prologue: tile 0, units in steady-state order Akh0,Bkh0,Akh1,Bkh1
  stage(0, 0, 0, 0);
  stage(0, 1, 0, 0);
  stage(0, 0, 1, 0);
  stage(0, 1, 1, 0);
  asm volatile("s_waitcnt vmcnt(4)" ::: "memory");  // kh0 pair ready
  __builtin_amdgcn_s_barrier();

  for (int t = 0; t < nt; ++t) {
    int buf = t & 1;
    bool hn = t + 1 < nt;
    int koff = (t + 1) * 64;
    const u16* Ac0 = S + ((buf * 2 + 0) * 2 + 0) * 8192;
    const u16* Ac1 = S + ((buf * 2 + 0) * 2 + 1) * 8192;
    const u16* Bc0 = S + ((buf * 2 + 1) * 2 + 0) * 8192;
    const u16* Bc1 = S + ((buf * 2 + 1) * 2 + 1) * 8192;
    bf16x8 aF[4], bF[4];
    GPHASE(Ac0, Bc0, 0, true, 0, 0, false)   // ks0 q0; stage A kh0 (t+1)
    GPHASE(Ac0, Bc0, 1, false, 1, 0, true)   // ks0 q1; stage B kh0; vmcnt(4)
    GPHASE(Ac1, Bc1, 0, true, 0, 1, false)   // ks1 q0; stage A kh1 (t+1)
    GPHASE(Ac1, Bc1, 1, false, 1, 1, true)   // ks1 q1; stage B kh1; vmcnt(4)
  }

  float* Cf = (float*)Cv + (size_t)blockIdx.z * M * N;
#pragma unroll
  for (int m = 0; m < 8; ++m)
#pragma unroll
    for (int n = 0; n < 4; ++n) {
      size_t base = (size_t)(m0 + wm * 128 + m * 16 + kb * 4) * N +
                    (n0 + wn * 64 + n * 16 + r15);
#pragma unroll
      for (int r = 0; r < 4; ++r) {
        size_t idx = base + (size_t)r * N;
        if (OUT == 0)
          Cf[idx] = acc[m][n][r];
        else if (OUT == 1)
          ((u16*)Cv)[idx] = f2bf(acc[m][n][r]);
        else
          ((u16*)Cv)[idx] = f2bf(siluf(bf2f(Aux[idx])) * acc[m][n][r]);
      }
    }
}

// -------- split-K reduce: out[i] = sum_s parts[s*n + i] ---------------------
__global__ __launch_bounds__(256) void reduce_kernel(
    const float* __restrict__ p, float* __restrict__ o, int n, int S) {
  int i = (blockIdx.x * 256 + threadIdx.x) * 4;
  f32x4 s = *(const f32x4*)(p + i);
  for (int j = 1; j < S; ++j) s += *(const f32x4*)(p + (size_t)j * n + i);
  *(f32x4*)(o + i) = s;
}

// -------- ba = hb(bf16) @ Wba(f32 [2048,64]) --------------------------------
__global__ __launch_bounds__(256) void ba_gemm_kernel(
    const u16* __restrict__ hb, const float* __restrict__ Wba,
    float* __restrict__ ba) {
  int m = blockIdx.x;
  int t = threadIdx.x;
  int n = t & 63, kq = t >> 6;
  const u16* a = hb + (size_t)m * DMODEL + kq * 512;
  const float* wp = Wba + (size_t)kq * 512 * 64 + n;
  float sum = 0.f;
  for (int i = 0; i < 512; ++i)
    sum += bf2f(a[i]) * wp[(size_t)i * 64];
  __shared__ float red[256];
  red[t] = sum;
  __syncthreads();
  if (t < 64)
    ba[(size_t)m * 64 + t] = red[t] + red[t + 64] + red[t + 128] + red[t + 192];
}

// -------- causal depthwise conv (K=4) + SiLU, bf16 in/out -------------------
__global__ __launch_bounds__(256) void conv_silu_kernel(
    const u16* __restrict__ qkvb, const float* __restrict__ conv_w,
    u16* __restrict__ qkv) {
  int gid = blockIdx.x * 256 + threadIdx.x;
  int c4 = (gid & 2047) * 4;
  int bt = gid >> 11;
  int b = bt >> 10, tt = bt & 1023;
  f32x4 wv[4];
#pragma unroll
  for (int j = 0; j < 4; ++j) wv[j] = *(const f32x4*)(conv_w + (c4 + j) * 4);
  float acc[4] = {0.f, 0.f, 0.f, 0.f};
#pragma unroll
  for (int i = 0; i < 4; ++i) {
    int ts = tt - 3 + i;
    if (ts >= 0) {
      u16x4 x = *(const u16x4*)(qkvb + (size_t)(b * 1024 + ts) * CONVC + c4);
#pragma unroll
      for (int j = 0; j < 4; ++j) acc[j] += bf2f(x[j]) * wv[j][i];
    }
  }
  u32x2 st;
  st[0] = pack2(siluf(acc[0]), siluf(acc[1]));
  st[1] = pack2(siluf(acc[2]), siluf(acc[3]));
  *(u32x2*)(qkv + (size_t)bt * CONVC + c4) = st;
}

// -------- l2 norm of q,k heads in place (bf16), q also * DK^-0.5 ------------
__global__ __launch_bounds__(256) void l2norm_kernel(u16* __restrict__ qkv) {
  int wid = blockIdx.x * 4 + (threadIdx.x >> 6);
  int l = threadIdx.x & 63;
  int tok = wid >> 5, slot = wid & 31;
  u16* p = qkv + (size_t)tok * CONVC + slot * 128 + l * 2;
  float x0 = bf2f(p[0]), x1 = bf2f(p[1]);
  float ss = x0 * x0 + x1 * x1;
#pragma unroll
  for (int m = 1; m < 64; m <<= 1) ss += __shfl_xor(ss, m, 64);
  float sc = rsqrtf(ss + 1e-6f);
  if (slot < 16) sc *= 0.08838834764831845f;  // DK^-0.5
  *(u32*)p = pack2(x0 * sc, x1 * sc);
}

// -------- bd[(b*32+h)][t][2] = {sigmoid(bb), exp(-exp(A_log)*softplus)} -----
__global__ __launch_bounds__(256) void betadecay_kernel(
    const float* __restrict__ ba, const float* __restrict__ A_log,
    const float* __restrict__ dt_bias, float* __restrict__ bd) {
  int idx = blockIdx.x * 256 + threadIdx.x;
  int h = idx & 31;
  int tok = idx >> 5;
  int b = tok >> 10, tt = tok & 1023;
  float bb = ba[(size_t)tok * 64 + h];
  float aa = ba[(size_t)tok * 64 + 32 + h];
  float bet = 1.f / (1.f + expf(-bb));
  float x = aa + dt_bias[h];
  float sp = (x > 20.f) ? x : log1pf(expf(x));
  float dec = expf(-expf(A_log[h]) * sp);
  size_t o = (((size_t)(b * 32 + h)) * 1024 + tt) * 2;
  bd[o] = bet;
  bd[o + 1] = dec;
}

// ======================= chunked delta-rule scan ============================
__global__ __launch_bounds__(256) void prep_kernel(
    const u16* __restrict__ qkvc, const float* __restrict__ bdpack,
    u16* __restrict__ Tg, u16* __restrict__ Pg, u16* __restrict__ KtTg,
    float* __restrict__ Bvec) {
  __shared__ __align__(16) u16 Kl[64 * 128];
  __shared__ __align__(16) u16 Ql[64 * 128];
  __shared__ __align__(16) float Af[64 * 65];
  __shared__ float bl[64], betal[64], sc63[64];
  int tid = threadIdx.x;
  int w = tid >> 6, l = tid & 63;
  int r15 = l & 15, kb = l >> 4;
  int c = blockIdx.x, bh = blockIdx.y;
  int b = bh >> 5, h = bh & 31, hk = h >> 1;
  size_t tok0 = (size_t)b * 1024 + c * 64;
  int ch = bh * 16 + c;

#pragma unroll
  for (int rep = 0; rep < 4; ++rep) {
    int gid = w * 256 + rep * 64 + l;
    int row = gid >> 4, seg = gid & 15;
    const u16* srcq = qkvc + (tok0 + row) * CONVC + hk * 128 + seg * 8;
    async16(srcq, Ql + gid * 8);
    async16(srcq + KEYDIM, Kl + gid * 8);
  }
  if (tid < 64) {
    size_t o = ((size_t)bh * 1024 + c * 64 + tid) * 2;
    betal[tid] = bdpack[o];
    float s = logf(fmaxf(bdpack[o + 1], 1e-30f));
#pragma unroll
    for (int d = 1; d < 64; d <<= 1) {
      float t = __shfl_up(s, d, 64);
      if (tid >= d) s += t;
    }
    bl[tid] = s;
    float tot = __shfl(s, 63, 64);
    sc63[tid] = expf(tot - s);
    Bvec[(size_t)ch * 64 + tid] = expf(s);
  }
  __syncthreads();

  {
    f32x4 akk[4] = {}, aqk[4] = {};
#pragma unroll
    for (int ks = 0; ks < 4; ++ks) {
      bf16x8 kaF = *(const bf16x8*)(Kl + (w * 16 + r15) * 128 + ks * 32 + kb * 8);
      bf16x8 qaF = *(const bf16x8*)(Ql + (w * 16 + r15) * 128 + ks * 32 + kb * 8);
#pragma unroll
      for (int n = 0; n < 4; ++n) {
        bf16x8 bF = *(const bf16x8*)(Kl + (n * 16 + r15) * 128 + ks * 32 + kb * 8);
        akk[n] = __builtin_amdgcn_mfma_f32_16x16x32_bf16(kaF, bF, akk[n], 0, 0, 0);
        aqk[n] = __builtin_amdgcn_mfma_f32_16x16x32_bf16(qaF, bF, aqk[n], 0, 0, 0);
      }
    }
#pragma unroll
    for (int n = 0; n < 4; ++n)
#pragma unroll
      for (int r = 0; r < 4; ++r) {
        int i = w * 16 + kb * 4 + r;
        int j = n * 16 + r15;
        float e = expf(bl[i] - bl[j]);
        Af[i * 65 + j] = (j < i) ? betal[i] * e * akk[n][r] : 0.f;
        u16 pv = (j <= i) ? f2bf(e * aqk[n][r]) : (u16)0;
        Pg[(size_t)ch * 4096 + i * 64 + j] = pv;
      }
  }
  for (int m = 0; m < 32; ++m) {
    int idx = tid * 32 + m;
    int d = idx >> 6, j = idx & 63;
    KtTg[(size_t)ch * 8192 + idx] = f2bf(bf2f(Kl[j * 128 + d]) * sc63[j]);
  }
  __syncthreads();

  {
    int ccol = w * 16 + r15;
    float tj[16];
#pragma unroll
    for (int m = 0; m < 16; ++m) tj[m] = (4 * m + kb == ccol) ? 1.f : 0.f;
#pragma unroll
    for (int i = 1; i < 64; ++i) {
      float part = 0.f;
      const int mb = (i + 3) >> 2;
#pragma unroll
      for (int m = 0; m < 16; ++m)
        if (m < mb) part = fmaf(Af[i * 65 + 4 * m + kb], tj[m], part);
      part += __shfl_xor(part, 16, 64);
      part += __shfl_xor(part, 32, 64);
      float nv = ((ccol == i) ? 1.f : 0.f) - part;
      if (kb == (i & 3)) tj[i >> 2] = nv;
    }
#pragma unroll
    for (int m = 0; m < 16; ++m)
      Tg[(size_t)ch * 4096 + (4 * m + kb) * 64 + ccol] = f2bf(tj[m]);
  }
}

__global__ __launch_bounds__(512) void chunk_scan_kernel(
    const u16* __restrict__ qkvc, const float* __restrict__ bdpack,
    const u16* __restrict__ Tg, const u16* __restrict__ Pg,
    const u16* __restrict__ KtTg, const float* __restrict__ Bvec,
    u16* __restrict__ obf) {
  __shared__ __align__(16) u16 Kl[64 * 128];
  __shared__ __align__(16) u16 Ql[64 * 128];
  __shared__ __align__(16) u16 KtTl[128 * 64];
  __shared__ __align__(16) u16 Tl[64 * 64];
  __shared__ __align__(16) u16 Pl[64 * 64];
  __shared__ __align__(16) u16 Vl[64 * 32];
  __shared__ __align__(16) u16 St[32 * 128];
  __shared__ __align__(16) u16 rhsT[32 * 64];
  __shared__ __align__(16) u16 dT[32 * 64];
  __shared__ float betal[64], Gl[64];

  int tid = threadIdx.x;
  int w = tid >> 6, l = tid & 63;
  int r15 = l & 15, kb = l >> 4;
  int dvc = blockIdx.x, bh = blockIdx.y;
  int b = bh >> 5, h = bh & 31, hk = h >> 1;
  int a = w >> 1, bcol = w & 1;

  for (int m = tid; m < 32 * 128; m += 512) St[m] = 0;
  f32x4 sAcc0 = {}, sAcc1 = {};
  __syncthreads();

  for (int c = 0; c < 16; ++c) {
    size_t tok0 = (size_t)b * 1024 + c * 64;
    int ch = bh * 16 + c;
#pragma unroll
    for (int rep = 0; rep < 2; ++rep) {
      int gid = w * 128 + rep * 64 + l;
      int row = gid >> 4, seg = gid & 15;
      const u16* srcq = qkvc + (tok0 + row) * CONVC + hk * 128 + seg * 8;
      async16(srcq, Ql + gid * 8);
      async16(srcq + KEYDIM, Kl + gid * 8);
      async16(KtTg + (size_t)ch * 8192 + gid * 8, KtTl + gid * 8);
    }
    {
      int gid = w * 64 + l;
      async16(Tg + (size_t)ch * 4096 + gid * 8, Tl + gid * 8);
      async16(Pg + (size_t)ch * 4096 + gid * 8, Pl + gid * 8);
    }
    if (w < 4) {
      int gid = w * 64 + l;
      int row = gid >> 2, seg = gid & 3;
      async16(qkvc + (tok0 + row) * CONVC + 2 * KEYDIM + h * 128 + dvc * 32 + seg * 8,
              Vl + gid * 8);
    }
    if (tid < 64) {
      betal[tid] = bdpack[((size_t)bh * 1024 + c * 64 + tid) * 2];
      Gl[tid] = Bvec[(size_t)ch * 64 + tid];
    }
    __syncthreads();

    f32x4 aKS = {}, aQS = {};
#pragma unroll
    for (int ks = 0; ks < 4; ++ks) {
      bf16x8 bF = *(const bf16x8*)(St + (bcol * 16 + r15) * 128 + ks * 32 + kb * 8);
      bf16x8 kF = *(const bf16x8*)(Kl + (a * 16 + r15) * 128 + ks * 32 + kb * 8);
      bf16x8 qF = *(const bf16x8*)(Ql + (a * 16 + r15) * 128 + ks * 32 + kb * 8);
      aKS = __builtin_amdgcn_mfma_f32_16x16x32_bf16(kF, bF, aKS, 0, 0, 0);
      aQS = __builtin_amdgcn_mfma_f32_16x16x32_bf16(qF, bF, aQS, 0, 0, 0);
    }
    {
      int i0 = a * 16 + kb * 4;
      int dv = bcol * 16 + r15;
      u16x4 st;
#pragma unroll
      for (int r = 0; r < 4; ++r) {
        int i = i0 + r;
        float v = bf2f(Vl[i * 32 + dv]);
        st[r] = f2bf(betal[i] * (v - Gl[i] * aKS[r]));
      }
      *(u16x4*)(rhsT + dv * 64 + i0) = st;
    }
    __syncthreads();
    f32x4 aD = {};
#pragma unroll
    for (int ks = 0; ks < 2; ++ks) {
      bf16x8 aF = *(const bf16x8*)(Tl + (a * 16 + r15) * 64 + ks * 32 + kb * 8);
      bf16x8 bF = *(const bf16x8*)(rhsT + (bcol * 16 + r15) * 64 + ks * 32 + kb * 8);
      aD = __builtin_amdgcn_mfma_f32_16x16x32_bf16(aF, bF, aD, 0, 0, 0);
    }
    {
      int i0 = a * 16 + kb * 4;
      int dv = bcol * 16 + r15;
      u16x4 st;
#pragma unroll
      for (int r = 0; r < 4; ++r) st[r] = f2bf(aD[r]);
      *(u16x4*)(dT + dv * 64 + i0) = st;
    }
    __syncthreads();
    f32x4 aO = {};
#pragma unroll
    for (int ks = 0; ks < 2; ++ks) {
      bf16x8 aF = *(const bf16x8*)(Pl + (a * 16 + r15) * 64 + ks * 32 + kb * 8);
      bf16x8 bF = *(const bf16x8*)(dT + (bcol * 16 + r15) * 64 + ks * 32 + kb * 8);
      aO = __builtin_amdgcn_mfma_f32_16x16x32_bf16(aF, bF, aO, 0, 0, 0);
    }
    {
      int i0 = a * 16 + kb * 4;
      int dv = bcol * 16 + r15;
#pragma unroll
      for (int r = 0; r < 4; ++r) {
        int i = i0 + r;
        float o = aO[r] + Gl[i] * aQS[r];
        obf[(tok0 + i) * VALDIM + h * 128 + dvc * 32 + dv] = f2bf(o);
      }
    }
    float gL = Gl[63];
#pragma unroll
    for (int r = 0; r < 4; ++r) { sAcc0[r] *= gL; sAcc1[r] *= gL; }
#pragma unroll
    for (int ks = 0; ks < 2; ++ks) {
      bf16x8 aF = *(const bf16x8*)(KtTl + (w * 16 + r15) * 64 + ks * 32 + kb * 8);
      bf16x8 b0 = *(const bf16x8*)(dT + r15 * 64 + ks * 32 + kb * 8);
      bf16x8 b1 = *(const bf16x8*)(dT + (16 + r15) * 64 + ks * 32 + kb * 8);
      sAcc0 = __builtin_amdgcn_mfma_f32_16x16x32_bf16(aF, b0, sAcc0, 0, 0, 0);
      sAcc1 = __builtin_amdgcn_mfma_f32_16x16x32_bf16(aF, b1, sAcc1, 0, 0, 0);
    }
#pragma unroll
    for (int r = 0; r < 4; ++r) {
      int dk = w * 16 + kb * 4 + r;
      St[r15 * 128 + dk] = f2bf(sAcc0[r]);
      St[(16 + r15) * 128 + dk] = f2bf(sAcc1[r]);
    }
    __syncthreads();
  }
}

// -------- gate (silu(z)) + per-head RMSNorm, in-place over z ----------------
__global__ __launch_bounds__(256) void gatenorm_kernel(
    const u16* __restrict__ obf, u16* __restrict__ zb,
    const float* __restrict__ norm_w) {
  int wid = blockIdx.x * 4 + (threadIdx.x >> 6);
  int l = threadIdx.x & 63;
  int tok = wid >> 5, h = wid & 31;
  const u16* op = obf + (size_t)tok * VALDIM + h * 128 + l * 2;
  u16* zp = zb + (size_t)tok * VALDIM + h * 128 + l * 2;
  float o0 = bf2f(op[0]), o1 = bf2f(op[1]);
  float z0 = bf2f(zp[0]), z1 = bf2f(zp[1]);
  float g0 = o0 * siluf(z0);
  float g1 = o1 * siluf(z1);
  float ss = g0 * g0 + g1 * g1;
#pragma unroll
  for (int m = 1; m < 64; m <<= 1) ss += __shfl_xor(ss, m, 64);
  float sc = rsqrtf(ss * (1.f / 128.f) + 1e-6f);
  int e = l * 2;
  *(u32*)zp = pack2(g0 * sc * norm_w[e], g1 * sc * norm_w[e + 1]);
}

// -------- diagnostic --------------------------------------------------------
__global__ void diag_kernel(float* out, float val) { out[0] = val; }

extern "C" void kernel_launch(void* const* d_in, const int* in_sizes, int n_in,
                              void* d_out, int out_size, void* d_ws,
                              size_t ws_size, hipStream_t stream) {
  const float* hidden = (const float*)d_in[1];
  const float* residual = (const float*)d_in[2];
  const float* ln_in_w = (const float*)d_in[3];
  const float* ln_post_w = (const float*)d_in[4];
  const float* Wqkvz = (const float*)d_in[5];
  const float* Wba = (const float*)d_in[6];
  const float* conv_w = (const float*)d_in[7];
  const float* A_log = (const float*)d_in[8];
  const float* dt_bias = (const float*)d_in[9];
  const float* norm_w = (const float*)d_in[10];
  const float* Wout = (const float*)d_in[11];
  const float* Wgate = (const float*)d_in[12];
  const float* Wup = (const float*)d_in[13];
  const float* Wdown = (const float*)d_in[14];

  char* ws = (char*)d_ws;
  size_t off = 0;
  auto alloc = [&](size_t n) {
    char* p = ws + off;
    off = (off + n + 255) & ~(size_t)255;
    return p;
  };
  u16* wslot = (u16*)alloc((size_t)INTER * DMODEL * 2);
  u16* hb = (u16*)alloc((size_t)BT * DMODEL * 2);
  u16* qkvb = (u16*)alloc((size_t)BT * CONVC * 2);
  u16* zb = (u16*)alloc((size_t)BT * VALDIM * 2);
  u16* qkvc = (u16*)alloc((size_t)BT * CONVC * 2);
  float* ba = (float*)alloc((size_t)BT * 64 * 4);
  float* bdpack = (float*)alloc((size_t)64 * 1024 * 2 * 4);
  u16* obf = (u16*)alloc((size_t)BT * VALDIM * 2);
  if (off > ws_size) {
    diag_kernel<<<1, 1, 0, stream>>>((float*)d_out, (float)(ws_size >> 20));
    return;
  }

  float* res1 = (float*)d_out;
  float* res2 = (float*)d_out + (size_t)BT * DMODEL;
  u16* h2b = hb;
  u16* gbuf = qkvc;
  u16* mbuf = qkvb;
  float* outp = (float*)d_out;

  u16* Tg = qkvb;
  u16* Pg = qkvb + (size_t)1024 * 4096;
  u16* KtTg = qkvb + (size_t)2 * 1024 * 4096;
  float* Bvec = ba;

  float* pWout = (float*)qkvb;  // 2 x 2048x2048 f32 (qkvb dead)
  float* pDown = (float*)zb;    // 4 x 2048x2048 f32 (zb..obf dead)

  dim3 blk(256);
  dim3 blk512(512);

  // 1. res1 = hidden+residual; hb = rmsnorm(res1)
  resnorm_kernel<<<BT, blk, 0, stream>>>(hidden, residual, ln_in_w, res1, hb);

  // 2. qkv-slice GEMM (256-tile 4-phase pipeline)
  convert_transpose<<<dim3(CONVC / 64, DMODEL / 64), blk, 0, stream>>>(
      Wqkvz, QKVZ_N, wslot, DMODEL, CONVC);
  gemm256_kernel<1><<<dim3(CONVC / 256, BT / 256), blk512, 0, stream>>>(
      hb, wslot, qkvb, nullptr, BT, CONVC, DMODEL, DMODEL);

  // 3. z-slice GEMM (128-tile)
  convert_transpose<<<dim3(VALDIM / 64, DMODEL / 64), blk, 0, stream>>>(
      Wqkvz + CONVC, QKVZ_N, wslot, DMODEL, VALDIM);
  gemm_kernel<1><<<dim3(VALDIM / 128, BT / 128), blk, 0, stream>>>(
      hb, wslot, zb, nullptr, BT, VALDIM, DMODEL, DMODEL);

  // 4. ba = hb @ Wba
  ba_gemm_kernel<<<BT, blk, 0, stream>>>(hb, Wba, ba);

  // 5-7. conv+silu, l2norm(q,k), beta/decay
  conv_silu_kernel<<<BT * 2048 / 256, blk, 0, stream>>>(qkvb, conv_w, qkvc);
  l2norm_kernel<<<BT * 32 / 4, blk, 0, stream>>>(qkvc);
  betadecay_kernel<<<BT * HV / 256, blk, 0, stream>>>(ba, A_log, dt_bias,
                                                      bdpack);

  // 8. chunked gated delta rule scan
  prep_kernel<<<dim3(16, 64), blk, 0, stream>>>(qkvc, bdpack, Tg, Pg, KtTg,
                                                Bvec);
  chunk_scan_kernel<<<dim3(4, 64), dim3(512), 0, stream>>>(
      qkvc, bdpack, Tg, Pg, KtTg, Bvec, obf);

  // 9. gate + per-head RMSNorm (in place over zb)
  gatenorm_kernel<<<BT * HV / 4, blk, 0, stream>>>(obf, zb, norm_w);

  // 10. Wout GEMM (128-tile, split-K=2, partials in dead qkvb)
  convert_transpose<<<dim3(DMODEL / 64, VALDIM / 64), blk, 0, stream>>>(
      Wout, DMODEL, wslot, VALDIM, DMODEL);
  gemm_kernel<0><<<dim3(DMODEL / 128, BT / 128, 2), blk, 0, stream>>>(
      zb, wslot, pWout, nullptr, BT, DMODEL, VALDIM, VALDIM / 2);

  // 11. res2 = p0+p1+res1 (fused reduce); h2b = rmsnorm(res2)
  resnorm2_kernel<<<BT, blk, 0, stream>>>(pWout, res1, ln_post_w, res2, h2b);

  // 12. gate GEMM (256-tile 4-phase)
  convert_transpose<<<dim3(INTER / 64, DMODEL / 64), blk, 0, stream>>>(
      Wgate, INTER, wslot, DMODEL, INTER);
  gemm256_kernel<1><<<dim3(INTER / 256, BT / 256), blk512, 0, stream>>>(
      h2b, wslot, gbuf, nullptr, BT, INTER, DMODEL, DMODEL);

  // 13. up GEMM fused with m = silu(g)*u (256-tile 4-phase)
  convert_transpose<<<dim3(INTER / 64, DMODEL / 64), blk, 0, stream>>>(
      Wup, INTER, wslot, DMODEL, INTER);
  gemm256_kernel<2><<<dim3(INTER / 256, BT / 256), blk512, 0, stream>>>(
      h2b, wslot, mbuf, gbuf, BT, INTER, DMODEL, DMODEL);

  // 14. out = m @ Wdown (256-tile 4-phase, split-K=4)
  convert_transpose<<<dim3(DMODEL / 64, INTER / 64), blk, 0, stream>>>(
      Wdown, DMODEL, wslot, INTER, DMODEL);
  gemm256_kernel<0><<<dim3(DMODEL / 256, BT / 256, 4), blk512, 0, stream>>>(
      mbuf, wslot, pDown, nullptr, BT, DMODEL, INTER, INTER / 4);
  reduce_kernel<<<BT * DMODEL / 1024, blk, 0, stream>>>(pDown, outp,
                                                        BT * DMODEL, 4);
}